// Round 15
// baseline (287.774 us; speedup 1.0000x reference)
//
#include <hip/hip_runtime.h>

typedef unsigned short u16;
typedef unsigned int u32;

#define B_    2
#define T_    2048
#define C_    2048
#define NH_   16
#define NKVH_ 4
#define HS_   128
#define NQKV  3072
#define M_    4096   // B*T
#define SCALE 0.08838834764831845f
#define CC    0.12751742f     // SCALE * log2(e)
#define THR_RAW 62.0f         // defer-max threshold (raw-score units, ~8/CC)

typedef __bf16 bf16x8 __attribute__((ext_vector_type(8)));
typedef float  f32x4  __attribute__((ext_vector_type(4)));
typedef float  f32x16 __attribute__((ext_vector_type(16)));
typedef unsigned int u32x2 __attribute__((ext_vector_type(2)));

__device__ __forceinline__ float bf2f(u16 u) {
    union { u32 i; float f; } x; x.i = ((u32)u) << 16; return x.f;
}
__device__ __forceinline__ u16 f2bf(float f) {
    union { float f; u32 i; } x; x.f = f;
    u32 r = x.i + 0x7fffu + ((x.i >> 16) & 1u);
    return (u16)(r >> 16);
}
__device__ __forceinline__ u32 pack2bf(float lo, float hi) {
    return (u32)f2bf(lo) | ((u32)f2bf(hi) << 16);
}
__device__ __forceinline__ u32 cvtpk(float lo, float hi) {
    u32 r; asm("v_cvt_pk_bf16_f32 %0, %1, %2" : "=v"(r) : "v"(lo), "v"(hi));
    return r;
}

// async global->LDS, 16B per lane; LDS dest = wave-uniform base + lane*16
__device__ __forceinline__ void gload16(const void* g, void* l) {
    __builtin_amdgcn_global_load_lds(
        (const __attribute__((address_space(1))) u32*)g,
        (__attribute__((address_space(3))) u32*)l,
        16, 0, 0);
}

// ---------------- cast x (f32 -> bf16) ----------------
__global__ __launch_bounds__(256) void cast_f32_bf16(
    const float* __restrict__ in, u16* __restrict__ out, int n)
{
    int idx = (blockIdx.x * 256 + threadIdx.x) * 4;
    if (idx < n) {
        float4 v = *reinterpret_cast<const float4*>(in + idx);
        u32 p0 = (u32)f2bf(v.x) | ((u32)f2bf(v.y) << 16);
        u32 p1 = (u32)f2bf(v.z) | ((u32)f2bf(v.w) << 16);
        u32* o = (u32*)(out + idx);
        o[0] = p0; o[1] = p1;
    }
}

// ---------------- transpose + cast (f32 RxC -> bf16 CxR) ----------------
__global__ __launch_bounds__(256) void transpose_cast_f32_bf16(
    const float* __restrict__ in, u16* __restrict__ out, int R, int Cc)
{
    __shared__ float tile[32][33];
    int c0 = blockIdx.x * 32, r0 = blockIdx.y * 32;
    int tx = threadIdx.x & 31, ty = threadIdx.x >> 5;  // 32 x 8
#pragma unroll
    for (int i = 0; i < 4; ++i)
        tile[ty + i * 8][tx] = in[(size_t)(r0 + ty + i * 8) * Cc + c0 + tx];
    __syncthreads();
#pragma unroll
    for (int i = 0; i < 4; ++i)
        out[(size_t)(c0 + ty + i * 8) * R + r0 + tx] = f2bf(tile[tx][ty + i * 8]);
}

// ---------------- batched bf16 transpose (z, R, Cc) -> (z, Cc, R) ----------------
__global__ __launch_bounds__(256) void transpose_bf16_batched(
    const u16* __restrict__ in, u16* __restrict__ out, int R, int Cc)
{
    __shared__ u16 tile[32][33];
    int c0 = blockIdx.x * 32, r0 = blockIdx.y * 32;
    size_t zb = (size_t)blockIdx.z * R * Cc;
    int tx = threadIdx.x & 31, ty = threadIdx.x >> 5;
#pragma unroll
    for (int i = 0; i < 4; ++i)
        tile[ty + i * 8][tx] = in[zb + (size_t)(r0 + ty + i * 8) * Cc + c0 + tx];
    __syncthreads();
#pragma unroll
    for (int i = 0; i < 4; ++i)
        out[zb + (size_t)(c0 + ty + i * 8) * R + r0 + tx] = tile[tx][ty + i * 8];
}

// ======== 8-phase MFMA GEMM (R10 ledger; best measured configs) ========
#define STA(KT2, KK, BUF)                                                  \
  { _Pragma("unroll") for (int i_ = 0; i_ < LA; ++i_)                      \
      gload16(gA[i_] + ((KT2) << 6) + (KK) * 32,                           \
              (char*)&As[BUF][KK][0] + i_ * 8192 + w * 1024); }
#define STB(KT2, KK, BUF)                                                  \
  { _Pragma("unroll") for (int i_ = 0; i_ < 2; ++i_)                       \
      gload16(gB[i_] + ((KT2) << 6) + (KK) * 32,                           \
              (char*)&Bs[BUF][KK][0] + i_ * 8192 + w * 1024); }
#define RDA(DST, BUF, KK, MHALF)                                           \
  { _Pragma("unroll") for (int m_ = 0; m_ < MH; ++m_)                      \
      DST[m_] = *reinterpret_cast<const bf16x8*>(                          \
          aLane + ((BUF) * 2 + (KK)) * ABLKB + ((MHALF) * MH + m_) * 1024); }
#define RDB(DST, BUF, KK)                                                  \
  { _Pragma("unroll") for (int n_ = 0; n_ < 4; ++n_)                       \
      DST[n_] = *reinterpret_cast<const bf16x8*>(                          \
          bLane + ((BUF) * 2 + (KK)) * 16384 + n_ * 1024); }
#define VMW()                                                              \
  { if constexpr (MFRAG == 8) asm volatile("s_waitcnt vmcnt(8)" ::: "memory"); \
    else                      asm volatile("s_waitcnt vmcnt(6)" ::: "memory"); }
#define KBODY(KT, CUR)                                                     \
  {                                                                        \
    const int kt_ = (KT);                                                  \
    bf16x8 af0[MH], af1[MH], af2[MH], af3[MH], bf0[4], bf1[4];             \
    RDA(af0, CUR, 0, 0); RDB(bf0, CUR, 0); RDA(af1, CUR, 0, 1);            \
    __builtin_amdgcn_s_barrier();                                          \
    __builtin_amdgcn_s_setprio(1);                                         \
    _Pragma("unroll") for (int m = 0; m < MH; ++m)                         \
      _Pragma("unroll") for (int n = 0; n < 4; ++n)                        \
        acc[m][n] = __builtin_amdgcn_mfma_f32_16x16x32_bf16(               \
            af0[m], bf0[n], acc[m][n], 0, 0, 0);                           \
    __builtin_amdgcn_s_setprio(0);                                         \
    __builtin_amdgcn_s_barrier();                                          \
    RDA(af2, CUR, 1, 0); RDB(bf1, CUR, 1);                                 \
    if (kt_ + 2 < NT) { STA(kt_ + 2, 0, CUR); STB(kt_ + 2, 0, CUR); }      \
    __builtin_amdgcn_s_barrier();                                          \
    __builtin_amdgcn_s_setprio(1);                                         \
    _Pragma("unroll") for (int m = 0; m < MH; ++m)                         \
      _Pragma("unroll") for (int n = 0; n < 4; ++n)                        \
        acc[MH + m][n] = __builtin_amdgcn_mfma_f32_16x16x32_bf16(          \
            af1[m], bf0[n], acc[MH + m][n], 0, 0, 0);                      \
    __builtin_amdgcn_s_setprio(0);                                         \
    __builtin_amdgcn_s_barrier();                                          \
    RDA(af3, CUR, 1, 1);                                                   \
    if (kt_ + 2 < NT) STB(kt_ + 2, 1, CUR);                                \
    __builtin_amdgcn_s_barrier();                                          \
    __builtin_amdgcn_s_setprio(1);                                         \
    _Pragma("unroll") for (int m = 0; m < MH; ++m)                         \
      _Pragma("unroll") for (int n = 0; n < 4; ++n)                        \
        acc[m][n] = __builtin_amdgcn_mfma_f32_16x16x32_bf16(               \
            af2[m], bf1[n], acc[m][n], 0, 0, 0);                           \
    __builtin_amdgcn_s_setprio(0);                                         \
    __builtin_amdgcn_s_barrier();                                          \
    if (kt_ + 2 < NT) STA(kt_ + 2, 1, CUR);                                \
    __builtin_amdgcn_s_barrier();                                          \
    __builtin_amdgcn_s_setprio(1);                                         \
    _Pragma("unroll") for (int m = 0; m < MH; ++m)                         \
      _Pragma("unroll") for (int n = 0; n < 4; ++n)                        \
        acc[MH + m][n] = __builtin_amdgcn_mfma_f32_16x16x32_bf16(          \
            af3[m], bf1[n], acc[MH + m][n], 0, 0, 0);                      \
    __builtin_amdgcn_s_setprio(0);                                         \
    if (kt_ + 1 < NT) {                                                    \
      if (kt_ + 2 < NT) { VMW(); }                                         \
      else { asm volatile("s_waitcnt vmcnt(0)" ::: "memory"); }            \
    }                                                                      \
    __builtin_amdgcn_s_barrier();                                          \
  }

template <int MFRAG, int OUT_BF16>
__global__ __launch_bounds__(512, 2) void gemm8(
    const u16* __restrict__ A, const u16* __restrict__ Bt,
    const float* __restrict__ bias, void* __restrict__ Cv,
    int M, int N, int K)
{
    constexpr int MH = MFRAG / 2;
    constexpr int LA = MFRAG / 4;
    constexpr int ABLKB = MFRAG * 2048;
    __shared__ __attribute__((aligned(16))) u16 As[2][2][MFRAG * 1024];
    __shared__ __attribute__((aligned(16))) u16 Bs[2][2][8192];

    int tid = threadIdx.x, lane = tid & 63, w = tid >> 6;
    int l16 = lane & 15, hi = (lane >> 4) & 3;
    int wm = w >> 2, wn = w & 3;

    int gx = gridDim.x, nwg = gx * gridDim.y;
    int id = blockIdx.y * gx + blockIdx.x;
    int nid = (id & 7) * (nwg >> 3) + (id >> 3);
    int brow = (nid % gx) * (MFRAG * 32), bcol = (nid / gx) * 256;

    const int NT = K >> 6;
    f32x4 acc[MFRAG][4] = {};

    u32 abase = (u32)l16 * 64 + (u32)hi * 16;
    u32 aoff  = abase ^ (((abase >> 7) & 7) << 4);
    const char* aLane = (const char*)&As[0][0][0] + wm * (MFRAG * 1024) + aoff;
    const char* bLane = (const char*)&Bs[0][0][0] + wn * 4096 + aoff;

    const u16* gA[LA];
    const u16* gB[2];
#pragma unroll
    for (int i = 0; i < LA; ++i) {
        u32 off = (u32)i * 8192 + (u32)w * 1024 + ((u32)lane << 4);
        u32 g = off ^ (((off >> 7) & 7) << 4);
        gA[i] = A + (size_t)(brow + (g >> 6)) * K + ((g >> 4) & 3) * 8;
    }
#pragma unroll
    for (int i = 0; i < 2; ++i) {
        u32 off = (u32)i * 8192 + (u32)w * 1024 + ((u32)lane << 4);
        u32 g = off ^ (((off >> 7) & 7) << 4);
        gB[i] = Bt + (size_t)(bcol + (g >> 6)) * K + ((g >> 4) & 3) * 8;
    }

    STA(0, 0, 0); STB(0, 0, 0); STA(0, 1, 0); STB(0, 1, 0);
    if (NT > 1) {
        STA(1, 0, 1); STB(1, 0, 1); STA(1, 1, 1); STB(1, 1, 1);
        VMW();
    } else {
        asm volatile("s_waitcnt vmcnt(0)" ::: "memory");
    }
    __builtin_amdgcn_s_barrier();

    for (int kt = 0; kt < NT; kt += 2) {
        KBODY(kt, 0);
        KBODY(kt + 1, 1);
    }

#pragma unroll
    for (int n = 0; n < 4; ++n) {
        int col = bcol + wn * 64 + n * 16 + l16;
        float bv = bias[col];
#pragma unroll
        for (int m = 0; m < MFRAG; ++m) {
#pragma unroll
            for (int j = 0; j < 4; ++j) {
                int row = brow + wm * (MFRAG * 16) + m * 16 + hi * 4 + j;
                float v = acc[m][n][j] + bv;
                if (OUT_BF16)
                    ((u16*)Cv)[(size_t)row * N + col] = f2bf(v);
                else
                    ((float*)Cv)[(size_t)row * N + col] = v;
            }
        }
    }
}
#undef STA
#undef STB
#undef RDA
#undef RDB
#undef VMW
#undef KBODY

// ---------------- RoPE + scatter q/k/v (u32/float2 vectorized) ----------------
__global__ __launch_bounds__(256) void rope_scatter(
    const u16* __restrict__ qkv,
    const float* __restrict__ fcos, const float* __restrict__ fsin,
    u16* __restrict__ qb, u16* __restrict__ kb, u16* __restrict__ vb,
    float* __restrict__ kc, float* __restrict__ vc)
{
    int bt = blockIdx.x;
    int b = bt >> 11, t = bt & 2047;
    const u16* row = qkv + (size_t)bt * NQKV;
#pragma unroll
    for (int s = threadIdx.x; s < NQKV / 2; s += 256) {
        int col = s * 2;
        u32 pair = *reinterpret_cast<const u32*>(row + col);
        float xr = bf2f((u16)pair), xi = bf2f((u16)(pair >> 16));
        if (col < C_) {                       // q
            int h = col >> 7, d = col & 127;
            int fi = t * 64 + (d >> 1);
            float c = fcos[fi], sn = fsin[fi];
            size_t o = ((size_t)(b * NH_ + h) * T_ + t) * HS_ + d;
            *reinterpret_cast<u32*>(qb + o) =
                pack2bf(xr * c - xi * sn, xr * sn + xi * c);
        } else if (col < C_ + NKVH_ * HS_) {  // k
            int cc = col - C_;
            int h = cc >> 7, d = cc & 127;
            int fi = t * 64 + (d >> 1);
            float c = fcos[fi], sn = fsin[fi];
            float yr = xr * c - xi * sn, yi = xr * sn + xi * c;
            size_t o = ((size_t)(b * NKVH_ + h) * T_ + t) * HS_ + d;
            *reinterpret_cast<u32*>(kb + o) = pack2bf(yr, yi);
            *reinterpret_cast<float2*>(kc + o) = make_float2(yr, yi);
        } else {                               // v
            int cc = col - (C_ + NKVH_ * HS_);
            int h = cc >> 7, d = cc & 127;
            size_t o = ((size_t)(b * NKVH_ + h) * T_ + t) * HS_ + d;
            *reinterpret_cast<u32*>(vb + o) = pair;
            *reinterpret_cast<float2*>(vc + o) = make_float2(xr, xi);
        }
    }
}

// ---------------- flash attention (causal, GQA), 32x32 swapped-QK ----------------
// R15: K double-buffered (32KB, 4-bit swizzle) + V SINGLE-buffered (16KB,
// 3-bit swizzle) = 48KB LDS -> 3 blocks/CU (was 2). V(it+1) staged after a
// post-PV barrier, consumed after next top barrier -> full compute-phase
// prefetch lead kept (unlike R14's zero-lead direct reads).
#define STAGE_K(it_, buf_)                                                \
  {                                                                       \
    int _it = (it_);                                                      \
    _Pragma("unroll")                                                     \
    for (int i = 0; i < 4; ++i) {                                         \
      int chunk = w * 4 + i;                                              \
      int rk = chunk * 4 + (lane >> 4);                                   \
      int ck = ((lane & 15) ^ (rk & 15)) << 3;                            \
      gload16(Kp + (size_t)(_it * 64 + rk) * HS_ + ck,                    \
              (char*)Ks[buf_] + chunk * 1024);                            \
    }                                                                     \
  }
#define STAGE_V(it_)                                                      \
  {                                                                       \
    int _it = (it_);                                                      \
    _Pragma("unroll")                                                     \
    for (int i = 0; i < 4; ++i) {                                         \
      int chunk = w * 4 + i;                                              \
      int rv = chunk * 8 + (lane >> 3);                                   \
      int cv = ((lane & 7) ^ (rv & 7)) << 3;                              \
      gload16(Vp + (size_t)rv * T_ + _it * 64 + cv,                       \
              (char*)Vs + chunk * 1024);                                  \
    }                                                                     \
  }

__global__ __launch_bounds__(256, 3) void attn_kernel(
    const u16* __restrict__ qb,   // (B, NH, T, HS)
    const u16* __restrict__ kb,   // (B, NKVH, T, HS)
    const u16* __restrict__ vt,   // (B, NKVH, HS, T)
    u16* __restrict__ aout)       // (B, T, C) bf16
{
    __shared__ __attribute__((aligned(16))) u16 Ks[2][64 * 128];
    __shared__ __attribute__((aligned(16))) u16 Vs[128 * 64];

    // load-balance remap: pair (n, n+256) gets qt summing to 15
    int xx = blockIdx.x, yy = blockIdx.y;
    int qt = (yy < 16) ? (15 - xx) : xx;
    int bh = yy, b = bh >> 4, h = bh & 15, kvh = h >> 2;
    int lane = threadIdx.x & 63, w = threadIdx.x >> 6;
    int l32 = lane & 31, l5 = lane >> 5;
    int xk = (l32 & 15) << 3;                // K-read XOR (row&15 == l32&15)
    int xv = (l32 & 7) << 3;                 // V-read XOR (row&7  == l32&7)
    int koff = 8 * l5;

    const u16* Qp = qb + ((size_t)(b * NH_ + h) * T_ + qt * 128 + w * 32) * HS_;
    const u16* Kp = kb + (size_t)(b * NKVH_ + kvh) * T_ * HS_;
    const u16* Vp = vt + (size_t)(b * NKVH_ + kvh) * HS_ * T_;

    // Q as B-operand frags: row = l32 (q), k = kd*16 + 8*l5 + [0..7]
    bf16x8 qf[8];
#pragma unroll
    for (int kd = 0; kd < 8; ++kd)
        qf[kd] = *reinterpret_cast<const bf16x8*>(
            Qp + (size_t)l32 * HS_ + kd * 16 + koff);

    f32x16 o[4] = {};
    float m = -1e30f, lrow = 0.f;
    int qg = qt * 128 + w * 32 + l32;        // this lane's q row
    int qmaxw = qt * 128 + w * 32 + 31;

    int ntiles = 2 * qt + 2;
    STAGE_K(0, 0);
    STAGE_V(0);

    for (int it = 0; it < ntiles; ++it) {
        int buf = it & 1;
        __syncthreads();                     // K(it) + V(it) resident
        if (it + 1 < ntiles) STAGE_K(it + 1, buf ^ 1);

        if (it * 64 <= qmaxw) {              // wave has unmasked work here
            const u16* Kbase = Ks[buf];

            // ---- S = K Q^T : D[kv][q], q = l32 lane-local ----
            f32x16 sacc[2] = {};
#pragma unroll
            for (int kt2 = 0; kt2 < 2; ++kt2)
#pragma unroll
                for (int kd = 0; kd < 8; ++kd) {
                    bf16x8 kf = *reinterpret_cast<const bf16x8*>(
                        Kbase + (kt2 * 32 + l32) * 128 + ((kd * 16 + koff) ^ xk));
                    sacc[kt2] = __builtin_amdgcn_mfma_f32_32x32x16_bf16(
                        kf, qf[kd], sacc[kt2], 0, 0, 0);
                }

            // ---- causal mask (raw scores; exp folds the scale) ----
            if (it * 64 + 63 > qt * 128 + w * 32) {
#pragma unroll
                for (int kt2 = 0; kt2 < 2; ++kt2)
#pragma unroll
                    for (int r = 0; r < 16; ++r) {
                        int kvg = it * 64 + kt2 * 32 + (r & 3) + 8 * (r >> 2) + 4 * l5;
                        if (kvg > qg) sacc[kt2][r] = -1e30f;
                    }
            }

            // ---- row max (tree + 1 cross-half shuffle) ----
            float mx;
            {
                float t8[8];
#pragma unroll
                for (int i = 0; i < 8; ++i) {
                    float a = fmaxf(sacc[0][i], sacc[0][i + 8]);
                    float c = fmaxf(sacc[1][i], sacc[1][i + 8]);
                    t8[i] = fmaxf(a, c);
                }
                float t4a = fmaxf(t8[0], t8[1]), t4b = fmaxf(t8[2], t8[3]);
                float t4c = fmaxf(t8[4], t8[5]), t4d = fmaxf(t8[6], t8[7]);
                mx = fmaxf(fmaxf(t4a, t4b), fmaxf(t4c, t4d));
                mx = fmaxf(mx, __shfl_xor(mx, 32));
            }

            // ---- defer-max: rescale only when max grew past threshold ----
            if (!__all(mx <= m + THR_RAW)) {
                float nm = fmaxf(m, mx);
                float al = exp2f(CC * (m - nm));
                m = nm;
                lrow *= al;
#pragma unroll
                for (int r = 0; r < 16; ++r) {
                    float af = __shfl(al, (r & 3) + 8 * (r >> 2) + 4 * l5, 64);
                    o[0][r] *= af; o[1][r] *= af; o[2][r] *= af; o[3][r] *= af;
                }
            }
            float mcm = -CC * m;

            // ---- P = 2^(CC*s - CC*m), row sum ----
            f32x16 p[2];
#pragma unroll
            for (int kt2 = 0; kt2 < 2; ++kt2)
#pragma unroll
                for (int r = 0; r < 16; ++r)
                    p[kt2][r] = exp2f(__builtin_fmaf(CC, sacc[kt2][r], mcm));
            {
                float s8[8];
#pragma unroll
                for (int i = 0; i < 8; ++i)
                    s8[i] = (p[0][i] + p[0][i + 8]) + (p[1][i] + p[1][i + 8]);
                float s4a = s8[0] + s8[1], s4b = s8[2] + s8[3];
                float s4c = s8[4] + s8[5], s4d = s8[6] + s8[7];
                float rs = (s4a + s4b) + (s4c + s4d);
                rs += __shfl_xor(rs, 32);
                lrow += rs;
            }

            // ---- PV: build A-frags in-register (cvt_pk + permlane32_swap) ----
#pragma unroll
            for (int ks = 0; ks < 4; ++ks) {
                int e = ks & 1, kh = ks >> 1;
                u32 a0 = cvtpk(p[kh][8 * e + 0], p[kh][8 * e + 1]);
                u32 a1 = cvtpk(p[kh][8 * e + 2], p[kh][8 * e + 3]);
                u32 b0 = cvtpk(p[kh][8 * e + 4], p[kh][8 * e + 5]);
                u32 b1 = cvtpk(p[kh][8 * e + 6], p[kh][8 * e + 7]);
                u32x2 s0 = __builtin_amdgcn_permlane32_swap(a0, b0, false, false);
                u32x2 s1 = __builtin_amdgcn_permlane32_swap(a1, b1, false, false);
                union { u32 u[4]; bf16x8 v; } pu;
                pu.u[0] = s0[0]; pu.u[1] = s1[0]; pu.u[2] = s0[1]; pu.u[3] = s1[1];
                bf16x8 pf = pu.v;
#pragma unroll
                for (int dt = 0; dt < 4; ++dt) {
                    bf16x8 vf = *reinterpret_cast<const bf16x8*>(
                        Vs + (dt * 32 + l32) * 64 + ((ks * 16 + koff) ^ xv));
                    o[dt] = __builtin_amdgcn_mfma_f32_32x32x16_bf16(
                        pf, vf, o[dt], 0, 0, 0);
                }
            }
        }

        __syncthreads();                     // all PV reads of Vs done
        if (it + 1 < ntiles) STAGE_V(it + 1);
    }

    // ---- epilogue: normalize (broadcast 1/l to reg-dim) and store ----
    float inv = 1.0f / lrow;
#pragma unroll
    for (int r = 0; r < 16; ++r) {
        int ql = (r & 3) + 8 * (r >> 2) + 4 * l5;
        float iv = __shfl(inv, ql, 64);
        int trow = qt * 128 + w * 32 + ql;
        size_t base = ((size_t)b * T_ + trow) * C_ + h * HS_ + l32;
#pragma unroll
        for (int dt = 0; dt < 4; ++dt)
            aout[base + dt * 32] = f2bf(o[dt][r] * iv);
    }
}

// ---------------- launch ----------------
extern "C" void kernel_launch(void* const* d_in, const int* in_sizes, int n_in,
                              void* d_out, int out_size, void* d_ws, size_t ws_size,
                              hipStream_t stream)
{
    const float* x      = (const float*)d_in[0];
    const float* w_qkv  = (const float*)d_in[1];
    const float* b_qkv  = (const float*)d_in[2];
    const float* w_proj = (const float*)d_in[3];
    const float* b_proj = (const float*)d_in[4];
    const float* fcos   = (const float*)d_in[5];
    const float* fsin   = (const float*)d_in[6];

    float* y  = (float*)d_out;
    float* kc = y + (size_t)B_ * T_ * C_;
    float* vc = kc + (size_t)B_ * NKVH_ * T_ * HS_;

    // R5-proven workspace layout (71.3 MB)
    char* ws = (char*)d_ws;
    u16* xb     = (u16*)(ws);
    u16* wprojT = (u16*)(ws);
    u16* wqkvT = (u16*)(ws + 16777216);
    u16* kbuf  = (u16*)(ws + 16777216);
    u16* vbuf  = (u16*)(ws + 16777216 + 4194304);
    u16* vtb   = (u16*)(ws + 16777216 + 8388608);
    u16* qkv  = (u16*)(ws + 29360128);
    u16* aout = (u16*)(ws + 29360128);
    u16* qbuf = (u16*)(ws + 54525952);

    cast_f32_bf16<<<M_ * C_ / 1024, 256, 0, stream>>>(x, xb, M_ * C_);
    transpose_cast_f32_bf16<<<dim3(NQKV / 32, C_ / 32), 256, 0, stream>>>(
        w_qkv, wqkvT, C_, NQKV);
    gemm8<8, 1><<<dim3(M_ / 256, NQKV / 256), 512, 0, stream>>>(
        xb, wqkvT, b_qkv, qkv, M_, NQKV, C_);
    rope_scatter<<<M_, 256, 0, stream>>>(qkv, fcos, fsin, qbuf, kbuf, vbuf, kc, vc);
    transpose_bf16_batched<<<dim3(HS_ / 32, T_ / 32, B_ * NKVH_), 256, 0, stream>>>(
        vbuf, vtb, T_, HS_);
    transpose_cast_f32_bf16<<<dim3(C_ / 32, C_ / 32), 256, 0, stream>>>(
        w_proj, wprojT, C_, C_);
    attn_kernel<<<dim3(T_ / 128, B_ * NH_), 256, 0, stream>>>(qbuf, kbuf, vtb, aout);
    gemm8<4, 0><<<dim3(M_ / 128, C_ / 256), 512, 0, stream>>>(
        aout, wprojT, b_proj, y, M_, C_, C_);
}

// Round 16
// 223.735 us; speedup vs baseline: 1.2862x; 1.2862x over previous
//
#include <hip/hip_runtime.h>

typedef unsigned short u16;
typedef unsigned int u32;

#define B_    2
#define T_    2048
#define C_    2048
#define NH_   16
#define NKVH_ 4
#define HS_   128
#define NQKV  3072
#define M_    4096   // B*T
#define SCALE 0.08838834764831845f
#define CC    0.12751742f     // SCALE * log2(e)
#define THR_RAW 62.0f         // defer-max threshold (raw-score units, ~8/CC)

typedef __bf16 bf16x8 __attribute__((ext_vector_type(8)));
typedef float  f32x4  __attribute__((ext_vector_type(4)));
typedef float  f32x16 __attribute__((ext_vector_type(16)));
typedef unsigned int u32x2 __attribute__((ext_vector_type(2)));

__device__ __forceinline__ float bf2f(u16 u) {
    union { u32 i; float f; } x; x.i = ((u32)u) << 16; return x.f;
}
__device__ __forceinline__ u16 f2bf(float f) {
    union { float f; u32 i; } x; x.f = f;
    u32 r = x.i + 0x7fffu + ((x.i >> 16) & 1u);
    return (u16)(r >> 16);
}
__device__ __forceinline__ u32 pack2bf(float lo, float hi) {
    return (u32)f2bf(lo) | ((u32)f2bf(hi) << 16);
}
__device__ __forceinline__ u32 cvtpk(float lo, float hi) {
    u32 r; asm("v_cvt_pk_bf16_f32 %0, %1, %2" : "=v"(r) : "v"(lo), "v"(hi));
    return r;
}

// async global->LDS, 16B per lane; LDS dest = wave-uniform base + lane*16
__device__ __forceinline__ void gload16(const void* g, void* l) {
    __builtin_amdgcn_global_load_lds(
        (const __attribute__((address_space(1))) u32*)g,
        (__attribute__((address_space(3))) u32*)l,
        16, 0, 0);
}

// ---------------- cast x (f32 -> bf16) ----------------
__global__ __launch_bounds__(256) void cast_f32_bf16(
    const float* __restrict__ in, u16* __restrict__ out, int n)
{
    int idx = (blockIdx.x * 256 + threadIdx.x) * 4;
    if (idx < n) {
        float4 v = *reinterpret_cast<const float4*>(in + idx);
        u32 p0 = (u32)f2bf(v.x) | ((u32)f2bf(v.y) << 16);
        u32 p1 = (u32)f2bf(v.z) | ((u32)f2bf(v.w) << 16);
        u32* o = (u32*)(out + idx);
        o[0] = p0; o[1] = p1;
    }
}

// ---------------- transpose + cast (f32 RxC -> bf16 CxR) ----------------
__global__ __launch_bounds__(256) void transpose_cast_f32_bf16(
    const float* __restrict__ in, u16* __restrict__ out, int R, int Cc)
{
    __shared__ float tile[32][33];
    int c0 = blockIdx.x * 32, r0 = blockIdx.y * 32;
    int tx = threadIdx.x & 31, ty = threadIdx.x >> 5;  // 32 x 8
#pragma unroll
    for (int i = 0; i < 4; ++i)
        tile[ty + i * 8][tx] = in[(size_t)(r0 + ty + i * 8) * Cc + c0 + tx];
    __syncthreads();
#pragma unroll
    for (int i = 0; i < 4; ++i)
        out[(size_t)(c0 + ty + i * 8) * R + r0 + tx] = f2bf(tile[tx][ty + i * 8]);
}

// ---------------- batched bf16 transpose (z, R, Cc) -> (z, Cc, R) ----------------
__global__ __launch_bounds__(256) void transpose_bf16_batched(
    const u16* __restrict__ in, u16* __restrict__ out, int R, int Cc)
{
    __shared__ u16 tile[32][33];
    int c0 = blockIdx.x * 32, r0 = blockIdx.y * 32;
    size_t zb = (size_t)blockIdx.z * R * Cc;
    int tx = threadIdx.x & 31, ty = threadIdx.x >> 5;
#pragma unroll
    for (int i = 0; i < 4; ++i)
        tile[ty + i * 8][tx] = in[zb + (size_t)(r0 + ty + i * 8) * Cc + c0 + tx];
    __syncthreads();
#pragma unroll
    for (int i = 0; i < 4; ++i)
        out[zb + (size_t)(c0 + ty + i * 8) * R + r0 + tx] = tile[tx][ty + i * 8];
}

// ======== 8-phase MFMA GEMM: C[M,N] = A[M,K]*Bt[N,K]^T + bias ========
// R9 schedule (best measured, 224.09 us total): lane-constant hoisted LDS
// bases + compile-time buffer/kk (K-loop unrolled by 2); stage points
// B1(kt+1)@P0, A0(kt+2)@P1, B0(kt+2)@P2, A1(kt+2)@P3; end-of-tile
// vmcnt(2*LA+LB) counted wait.
#define STA(KT2, KK, BUF)                                                  \
  { _Pragma("unroll") for (int i_ = 0; i_ < LA; ++i_)                      \
      gload16(gA[i_] + ((KT2) << 6) + (KK) * 32,                           \
              (char*)&As[BUF][KK][0] + i_ * 8192 + w * 1024); }
#define STB(KT2, KK, BUF)                                                  \
  { _Pragma("unroll") for (int i_ = 0; i_ < 2; ++i_)                       \
      gload16(gB[i_] + ((KT2) << 6) + (KK) * 32,                           \
              (char*)&Bs[BUF][KK][0] + i_ * 8192 + w * 1024); }
#define RDA(DST, BUF, KK, MHALF)                                           \
  { _Pragma("unroll") for (int m_ = 0; m_ < MH; ++m_)                      \
      DST[m_] = *reinterpret_cast<const bf16x8*>(                          \
          aLane + ((BUF) * 2 + (KK)) * ABLKB + ((MHALF) * MH + m_) * 1024); }
#define RDB(DST, BUF, KK)                                                  \
  { _Pragma("unroll") for (int n_ = 0; n_ < 4; ++n_)                       \
      DST[n_] = *reinterpret_cast<const bf16x8*>(                          \
          bLane + ((BUF) * 2 + (KK)) * 16384 + n_ * 1024); }
#define KBODY(KT, CUR)                                                     \
  {                                                                        \
    const int kt_ = (KT);                                                  \
    bf16x8 af0[MH], af1[MH], af2[MH], af3[MH], bf0[4], bf1[4];             \
    RDA(af0, CUR, 0, 0); RDB(bf0, CUR, 0); RDA(af1, CUR, 0, 1);            \
    if (kt_ + 1 < NT) STB(kt_ + 1, 1, CUR ^ 1);                            \
    __builtin_amdgcn_s_barrier();                                          \
    __builtin_amdgcn_s_setprio(1);                                         \
    _Pragma("unroll") for (int m = 0; m < MH; ++m)                         \
      _Pragma("unroll") for (int n = 0; n < 4; ++n)                        \
        acc[m][n] = __builtin_amdgcn_mfma_f32_16x16x32_bf16(               \
            af0[m], bf0[n], acc[m][n], 0, 0, 0);                           \
    __builtin_amdgcn_s_setprio(0);                                         \
    __builtin_amdgcn_s_barrier();                                          \
    RDA(af2, CUR, 1, 0); RDB(bf1, CUR, 1);                                 \
    if (kt_ + 2 < NT) STA(kt_ + 2, 0, CUR);                                \
    __builtin_amdgcn_s_barrier();                                          \
    __builtin_amdgcn_s_setprio(1);                                         \
    _Pragma("unroll") for (int m = 0; m < MH; ++m)                         \
      _Pragma("unroll") for (int n = 0; n < 4; ++n)                        \
        acc[MH + m][n] = __builtin_amdgcn_mfma_f32_16x16x32_bf16(          \
            af1[m], bf0[n], acc[MH + m][n], 0, 0, 0);                      \
    __builtin_amdgcn_s_setprio(0);                                         \
    __builtin_amdgcn_s_barrier();                                          \
    RDA(af3, CUR, 1, 1);                                                   \
    if (kt_ + 2 < NT) STB(kt_ + 2, 0, CUR);                                \
    __builtin_amdgcn_s_barrier();                                          \
    __builtin_amdgcn_s_setprio(1);                                         \
    _Pragma("unroll") for (int m = 0; m < MH; ++m)                         \
      _Pragma("unroll") for (int n = 0; n < 4; ++n)                        \
        acc[m][n] = __builtin_amdgcn_mfma_f32_16x16x32_bf16(               \
            af2[m], bf1[n], acc[m][n], 0, 0, 0);                           \
    __builtin_amdgcn_s_setprio(0);                                         \
    __builtin_amdgcn_s_barrier();                                          \
    if (kt_ + 2 < NT) STA(kt_ + 2, 1, CUR);                                \
    __builtin_amdgcn_s_barrier();                                          \
    __builtin_amdgcn_s_setprio(1);                                         \
    _Pragma("unroll") for (int m = 0; m < MH; ++m)                         \
      _Pragma("unroll") for (int n = 0; n < 4; ++n)                        \
        acc[MH + m][n] = __builtin_amdgcn_mfma_f32_16x16x32_bf16(          \
            af3[m], bf1[n], acc[MH + m][n], 0, 0, 0);                      \
    __builtin_amdgcn_s_setprio(0);                                         \
    if (kt_ + 1 < NT) {                                                    \
      if (kt_ + 2 < NT) {                                                  \
        if constexpr (MFRAG == 8)                                          \
          asm volatile("s_waitcnt vmcnt(6)" ::: "memory");                 \
        else                                                               \
          asm volatile("s_waitcnt vmcnt(4)" ::: "memory");                 \
      } else {                                                             \
        asm volatile("s_waitcnt vmcnt(0)" ::: "memory");                   \
      }                                                                    \
    }                                                                      \
    __builtin_amdgcn_s_barrier();                                          \
  }

template <int MFRAG, int OUT_BF16>
__global__ __launch_bounds__(512, 2) void gemm8(
    const u16* __restrict__ A, const u16* __restrict__ Bt,
    const float* __restrict__ bias, void* __restrict__ Cv,
    int M, int N, int K)
{
    constexpr int MH = MFRAG / 2;        // m-frags per m-half
    constexpr int LA = MFRAG / 4;        // gload16 per A half-tile per wave
    constexpr int ABLKB = MFRAG * 2048;  // bytes per As[buf][kk] block
    __shared__ __attribute__((aligned(16))) u16 As[2][2][MFRAG * 1024];
    __shared__ __attribute__((aligned(16))) u16 Bs[2][2][8192];

    int tid = threadIdx.x, lane = tid & 63, w = tid >> 6;
    int l16 = lane & 15, hi = (lane >> 4) & 3;
    int wm = w >> 2, wn = w & 3;

    // bijective XCD swizzle (nwg % 8 == 0 for all our grids)
    int gx = gridDim.x, nwg = gx * gridDim.y;
    int id = blockIdx.y * gx + blockIdx.x;
    int nid = (id & 7) * (nwg >> 3) + (id >> 3);
    int brow = (nid % gx) * (MFRAG * 32), bcol = (nid / gx) * 256;

    const int NT = K >> 6;
    f32x4 acc[MFRAG][4] = {};

    // hoisted lane-constant addressing
    u32 abase = (u32)l16 * 64 + (u32)hi * 16;
    u32 aoff  = abase ^ (((abase >> 7) & 7) << 4);
    const char* aLane = (const char*)&As[0][0][0] + wm * (MFRAG * 1024) + aoff;
    const char* bLane = (const char*)&Bs[0][0][0] + wn * 4096 + aoff;

    const u16* gA[LA];
    const u16* gB[2];
#pragma unroll
    for (int i = 0; i < LA; ++i) {
        u32 off = (u32)i * 8192 + (u32)w * 1024 + ((u32)lane << 4);
        u32 g = off ^ (((off >> 7) & 7) << 4);
        gA[i] = A + (size_t)(brow + (g >> 6)) * K + ((g >> 4) & 3) * 8;
    }
#pragma unroll
    for (int i = 0; i < 2; ++i) {
        u32 off = (u32)i * 8192 + (u32)w * 1024 + ((u32)lane << 4);
        u32 g = off ^ (((off >> 7) & 7) << 4);
        gB[i] = Bt + (size_t)(bcol + (g >> 6)) * K + ((g >> 4) & 3) * 8;
    }

    // prologue: tile0 all 4 halves + tile1 {A0, B0, A1}; drain tile0
    STA(0, 0, 0); STB(0, 0, 0); STA(0, 1, 0); STB(0, 1, 0);
    if (NT > 1) {
        STA(1, 0, 1); STB(1, 0, 1); STA(1, 1, 1);
        if constexpr (MFRAG == 8) asm volatile("s_waitcnt vmcnt(6)" ::: "memory");
        else                      asm volatile("s_waitcnt vmcnt(4)" ::: "memory");
    } else {
        asm volatile("s_waitcnt vmcnt(0)" ::: "memory");
    }
    __builtin_amdgcn_s_barrier();

    for (int kt = 0; kt < NT; kt += 2) {   // NT even (K=2048)
        KBODY(kt, 0);
        KBODY(kt + 1, 1);
    }

    // ---- epilogue ----
#pragma unroll
    for (int n = 0; n < 4; ++n) {
        int col = bcol + wn * 64 + n * 16 + l16;
        float bv = bias[col];
#pragma unroll
        for (int m = 0; m < MFRAG; ++m) {
#pragma unroll
            for (int j = 0; j < 4; ++j) {
                int row = brow + wm * (MFRAG * 16) + m * 16 + hi * 4 + j;
                float v = acc[m][n][j] + bv;
                if (OUT_BF16)
                    ((u16*)Cv)[(size_t)row * N + col] = f2bf(v);
                else
                    ((float*)Cv)[(size_t)row * N + col] = v;
            }
        }
    }
}
#undef STA
#undef STB
#undef RDA
#undef RDB
#undef KBODY

// ---------------- RoPE + scatter q/k/v (u32/float2 vectorized) ----------------
__global__ __launch_bounds__(256) void rope_scatter(
    const u16* __restrict__ qkv,
    const float* __restrict__ fcos, const float* __restrict__ fsin,
    u16* __restrict__ qb, u16* __restrict__ kb, u16* __restrict__ vb,
    float* __restrict__ kc, float* __restrict__ vc)
{
    int bt = blockIdx.x;
    int b = bt >> 11, t = bt & 2047;
    const u16* row = qkv + (size_t)bt * NQKV;
#pragma unroll
    for (int s = threadIdx.x; s < NQKV / 2; s += 256) {
        int col = s * 2;
        u32 pair = *reinterpret_cast<const u32*>(row + col);
        float xr = bf2f((u16)pair), xi = bf2f((u16)(pair >> 16));
        if (col < C_) {                       // q
            int h = col >> 7, d = col & 127;
            int fi = t * 64 + (d >> 1);
            float c = fcos[fi], sn = fsin[fi];
            size_t o = ((size_t)(b * NH_ + h) * T_ + t) * HS_ + d;
            *reinterpret_cast<u32*>(qb + o) =
                pack2bf(xr * c - xi * sn, xr * sn + xi * c);
        } else if (col < C_ + NKVH_ * HS_) {  // k
            int cc = col - C_;
            int h = cc >> 7, d = cc & 127;
            int fi = t * 64 + (d >> 1);
            float c = fcos[fi], sn = fsin[fi];
            float yr = xr * c - xi * sn, yi = xr * sn + xi * c;
            size_t o = ((size_t)(b * NKVH_ + h) * T_ + t) * HS_ + d;
            *reinterpret_cast<u32*>(kb + o) = pack2bf(yr, yi);
            *reinterpret_cast<float2*>(kc + o) = make_float2(yr, yi);
        } else {                               // v
            int cc = col - (C_ + NKVH_ * HS_);
            int h = cc >> 7, d = cc & 127;
            size_t o = ((size_t)(b * NKVH_ + h) * T_ + t) * HS_ + d;
            *reinterpret_cast<u32*>(vb + o) = pair;
            *reinterpret_cast<float2*>(vc + o) = make_float2(xr, xi);
        }
    }
}

// ---------------- flash attention (causal, GQA), 32x32 swapped-QK ----------------
// R4-verified form (84-85 us): QBLK=128 (4 waves x 32 q-rows), KVBLK=64,
// K/V dbuf + XOR-swizzle, sum-15 co-resident pairing, NO setprio (-5% measured).
#define STAGE_KV(it_, buf_)                                               \
  {                                                                       \
    int _it = (it_);                                                      \
    _Pragma("unroll")                                                     \
    for (int i = 0; i < 4; ++i) {                                         \
      int chunk = w * 4 + i;                                              \
      int rk = chunk * 4 + (lane >> 4);                                   \
      int ck = ((lane & 15) ^ (rk & 7)) << 3;                             \
      gload16(Kp + (size_t)(_it * 64 + rk) * HS_ + ck,                    \
              (char*)Ks[buf_] + chunk * 1024);                            \
      int rv = chunk * 8 + (lane >> 3);                                   \
      int cv = ((lane & 7) ^ (rv & 7)) << 3;                              \
      gload16(Vp + (size_t)rv * T_ + _it * 64 + cv,                       \
              (char*)Vs[buf_] + chunk * 1024);                            \
    }                                                                     \
  }

__global__ __launch_bounds__(256, 2) void attn_kernel(
    const u16* __restrict__ qb,   // (B, NH, T, HS)
    const u16* __restrict__ kb,   // (B, NKVH, T, HS)
    const u16* __restrict__ vt,   // (B, NKVH, HS, T)
    u16* __restrict__ aout)       // (B, T, C) bf16
{
    __shared__ __attribute__((aligned(16))) u16 Ks[2][64 * 128];
    __shared__ __attribute__((aligned(16))) u16 Vs[2][128 * 64];

    // load-balance remap: co-resident pair (n, n+256) gets qt summing to 15
    int xx = blockIdx.x, yy = blockIdx.y;
    int qt = (yy < 16) ? (15 - xx) : xx;
    int bh = yy, b = bh >> 4, h = bh & 15, kvh = h >> 2;
    int lane = threadIdx.x & 63, w = threadIdx.x >> 6;
    int l32 = lane & 31, l5 = lane >> 5;
    int xorm = (l32 & 7) << 3;               // element-space XOR for LDS reads
    int koff = 8 * l5;

    const u16* Qp = qb + ((size_t)(b * NH_ + h) * T_ + qt * 128 + w * 32) * HS_;
    const u16* Kp = kb + (size_t)(b * NKVH_ + kvh) * T_ * HS_;
    const u16* Vp = vt + (size_t)(b * NKVH_ + kvh) * HS_ * T_;

    // Q as B-operand frags: row = l32 (q), k = kd*16 + 8*l5 + [0..7]
    bf16x8 qf[8];
#pragma unroll
    for (int kd = 0; kd < 8; ++kd)
        qf[kd] = *reinterpret_cast<const bf16x8*>(
            Qp + (size_t)l32 * HS_ + kd * 16 + koff);

    f32x16 o[4] = {};
    float m = -1e30f, lrow = 0.f;
    int qg = qt * 128 + w * 32 + l32;        // this lane's q row
    int qmaxw = qt * 128 + w * 32 + 31;

    int ntiles = 2 * qt + 2;
    STAGE_KV(0, 0);

    for (int it = 0; it < ntiles; ++it) {
        int buf = it & 1;
        __syncthreads();                     // tile `it` resident
        if (it + 1 < ntiles) STAGE_KV(it + 1, buf ^ 1);

        if (it * 64 <= qmaxw) {              // wave has unmasked work here
            const u16* Kbase = Ks[buf];
            const u16* Vbase = Vs[buf];

            // ---- S = K Q^T : D[kv][q], q = l32 lane-local ----
            f32x16 sacc[2] = {};
#pragma unroll
            for (int kt2 = 0; kt2 < 2; ++kt2)
#pragma unroll
                for (int kd = 0; kd < 8; ++kd) {
                    bf16x8 kf = *reinterpret_cast<const bf16x8*>(
                        Kbase + (kt2 * 32 + l32) * 128 + ((kd * 16 + koff) ^ xorm));
                    sacc[kt2] = __builtin_amdgcn_mfma_f32_32x32x16_bf16(
                        kf, qf[kd], sacc[kt2], 0, 0, 0);
                }

            // ---- causal mask (raw scores; exp folds the scale) ----
            if (it * 64 + 63 > qt * 128 + w * 32) {
#pragma unroll
                for (int kt2 = 0; kt2 < 2; ++kt2)
#pragma unroll
                    for (int r = 0; r < 16; ++r) {
                        int kvg = it * 64 + kt2 * 32 + (r & 3) + 8 * (r >> 2) + 4 * l5;
                        if (kvg > qg) sacc[kt2][r] = -1e30f;
                    }
            }

            // ---- row max (tree + 1 cross-half shuffle) ----
            float mx;
            {
                float t8[8];
#pragma unroll
                for (int i = 0; i < 8; ++i) {
                    float a = fmaxf(sacc[0][i], sacc[0][i + 8]);
                    float c = fmaxf(sacc[1][i], sacc[1][i + 8]);
                    t8[i] = fmaxf(a, c);
                }
                float t4a = fmaxf(t8[0], t8[1]), t4b = fmaxf(t8[2], t8[3]);
                float t4c = fmaxf(t8[4], t8[5]), t4d = fmaxf(t8[6], t8[7]);
                mx = fmaxf(fmaxf(t4a, t4b), fmaxf(t4c, t4d));
                mx = fmaxf(mx, __shfl_xor(mx, 32));
            }

            // ---- defer-max: rescale only when max grew past threshold ----
            if (!__all(mx <= m + THR_RAW)) {
                float nm = fmaxf(m, mx);
                float al = exp2f(CC * (m - nm));
                m = nm;
                lrow *= al;
#pragma unroll
                for (int r = 0; r < 16; ++r) {
                    float af = __shfl(al, (r & 3) + 8 * (r >> 2) + 4 * l5, 64);
                    o[0][r] *= af; o[1][r] *= af; o[2][r] *= af; o[3][r] *= af;
                }
            }
            float mcm = -CC * m;

            // ---- P = 2^(CC*s - CC*m), row sum ----
            f32x16 p[2];
#pragma unroll
            for (int kt2 = 0; kt2 < 2; ++kt2)
#pragma unroll
                for (int r = 0; r < 16; ++r)
                    p[kt2][r] = exp2f(__builtin_fmaf(CC, sacc[kt2][r], mcm));
            {
                float s8[8];
#pragma unroll
                for (int i = 0; i < 8; ++i)
                    s8[i] = (p[0][i] + p[0][i + 8]) + (p[1][i] + p[1][i + 8]);
                float s4a = s8[0] + s8[1], s4b = s8[2] + s8[3];
                float s4c = s8[4] + s8[5], s4d = s8[6] + s8[7];
                float rs = (s4a + s4b) + (s4c + s4d);
                rs += __shfl_xor(rs, 32);
                lrow += rs;
            }

            // ---- PV: build A-frags in-register (cvt_pk + permlane32_swap) ----
#pragma unroll
            for (int ks = 0; ks < 4; ++ks) {
                int e = ks & 1, kh = ks >> 1;
                u32 a0 = cvtpk(p[kh][8 * e + 0], p[kh][8 * e + 1]);
                u32 a1 = cvtpk(p[kh][8 * e + 2], p[kh][8 * e + 3]);
                u32 b0 = cvtpk(p[kh][8 * e + 4], p[kh][8 * e + 5]);
                u32 b1 = cvtpk(p[kh][8 * e + 6], p[kh][8 * e + 7]);
                u32x2 s0 = __builtin_amdgcn_permlane32_swap(a0, b0, false, false);
                u32x2 s1 = __builtin_amdgcn_permlane32_swap(a1, b1, false, false);
                union { u32 u[4]; bf16x8 v; } pu;
                pu.u[0] = s0[0]; pu.u[1] = s1[0]; pu.u[2] = s0[1]; pu.u[3] = s1[1];
                bf16x8 pf = pu.v;
#pragma unroll
                for (int dt = 0; dt < 4; ++dt) {
                    bf16x8 vf = *reinterpret_cast<const bf16x8*>(
                        Vbase + (dt * 32 + l32) * 64 + ((ks * 16 + koff) ^ xorm));
                    o[dt] = __builtin_amdgcn_mfma_f32_32x32x16_bf16(
                        pf, vf, o[dt], 0, 0, 0);
                }
            }
        }
    }

    // ---- epilogue: normalize (broadcast 1/l to reg-dim) and store ----
    float inv = 1.0f / lrow;
#pragma unroll
    for (int r = 0; r < 16; ++r) {
        int ql = (r & 3) + 8 * (r >> 2) + 4 * l5;
        float iv = __shfl(inv, ql, 64);
        int trow = qt * 128 + w * 32 + ql;
        size_t base = ((size_t)b * T_ + trow) * C_ + h * HS_ + l32;
#pragma unroll
        for (int dt = 0; dt < 4; ++dt)
            aout[base + dt * 32] = f2bf(o[dt][r] * iv);
    }
}

// ---------------- launch ----------------
extern "C" void kernel_launch(void* const* d_in, const int* in_sizes, int n_in,
                              void* d_out, int out_size, void* d_ws, size_t ws_size,
                              hipStream_t stream)
{
    const float* x      = (const float*)d_in[0];
    const float* w_qkv  = (const float*)d_in[1];
    const float* b_qkv  = (const float*)d_in[2];
    const float* w_proj = (const float*)d_in[3];
    const float* b_proj = (const float*)d_in[4];
    const float* fcos   = (const float*)d_in[5];
    const float* fsin   = (const float*)d_in[6];

    float* y  = (float*)d_out;
    float* kc = y + (size_t)B_ * T_ * C_;
    float* vc = kc + (size_t)B_ * NKVH_ * T_ * HS_;

    // R5-proven workspace layout (71.3 MB)
    char* ws = (char*)d_ws;
    u16* xb     = (u16*)(ws);
    u16* wprojT = (u16*)(ws);
    u16* wqkvT = (u16*)(ws + 16777216);
    u16* kbuf  = (u16*)(ws + 16777216);
    u16* vbuf  = (u16*)(ws + 16777216 + 4194304);
    u16* vtb   = (u16*)(ws + 16777216 + 8388608);
    u16* qkv  = (u16*)(ws + 29360128);
    u16* aout = (u16*)(ws + 29360128);
    u16* qbuf = (u16*)(ws + 54525952);

    cast_f32_bf16<<<M_ * C_ / 1024, 256, 0, stream>>>(x, xb, M_ * C_);
    transpose_cast_f32_bf16<<<dim3(NQKV / 32, C_ / 32), 256, 0, stream>>>(
        w_qkv, wqkvT, C_, NQKV);
    gemm8<8, 1><<<dim3(M_ / 256, NQKV / 256), 512, 0, stream>>>(
        xb, wqkvT, b_qkv, qkv, M_, NQKV, C_);
    rope_scatter<<<M_, 256, 0, stream>>>(qkv, fcos, fsin, qbuf, kbuf, vbuf, kc, vc);
    transpose_bf16_batched<<<dim3(HS_ / 32, T_ / 32, B_ * NKVH_), 256, 0, stream>>>(
        vbuf, vtb, T_, HS_);
    transpose_cast_f32_bf16<<<dim3(C_ / 32, C_ / 32), 256, 0, stream>>>(
        w_proj, wprojT, C_, C_);
    attn_kernel<<<dim3(T_ / 128, B_ * NH_), 256, 0, stream>>>(qbuf, kbuf, vtb, aout);
    gemm8<4, 0><<<dim3(M_ / 128, C_ / 256), 512, 0, stream>>>(
        aout, wprojT, b_proj, y, M_, C_, C_);
}

// Round 17
// 215.108 us; speedup vs baseline: 1.3378x; 1.0401x over previous
//
#include <hip/hip_runtime.h>

typedef unsigned short u16;
typedef unsigned int u32;

#define B_    2
#define T_    2048
#define C_    2048
#define NH_   16
#define NKVH_ 4
#define HS_   128
#define NQKV  3072
#define M_    4096   // B*T
#define SCALE 0.08838834764831845f
#define CC    0.12751742f     // SCALE * log2(e)
#define THR_RAW 62.0f         // defer-max threshold (raw-score units, ~8/CC)

typedef __bf16 bf16x8 __attribute__((ext_vector_type(8)));
typedef float  f32x4  __attribute__((ext_vector_type(4)));
typedef float  f32x16 __attribute__((ext_vector_type(16)));
typedef unsigned int u32x2 __attribute__((ext_vector_type(2)));

__device__ __forceinline__ float bf2f(u16 u) {
    union { u32 i; float f; } x; x.i = ((u32)u) << 16; return x.f;
}
__device__ __forceinline__ u16 f2bf(float f) {
    union { float f; u32 i; } x; x.f = f;
    u32 r = x.i + 0x7fffu + ((x.i >> 16) & 1u);
    return (u16)(r >> 16);
}
__device__ __forceinline__ u32 pack2bf(float lo, float hi) {
    return (u32)f2bf(lo) | ((u32)f2bf(hi) << 16);
}
__device__ __forceinline__ u32 cvtpk(float lo, float hi) {
    u32 r; asm("v_cvt_pk_bf16_f32 %0, %1, %2" : "=v"(r) : "v"(lo), "v"(hi));
    return r;
}

// async global->LDS, 16B per lane; LDS dest = wave-uniform base + lane*16
__device__ __forceinline__ void gload16(const void* g, void* l) {
    __builtin_amdgcn_global_load_lds(
        (const __attribute__((address_space(1))) u32*)g,
        (__attribute__((address_space(3))) u32*)l,
        16, 0, 0);
}

// ---------------- cast x (f32 -> bf16) ----------------
__global__ __launch_bounds__(256) void cast_f32_bf16(
    const float* __restrict__ in, u16* __restrict__ out, int n)
{
    int idx = (blockIdx.x * 256 + threadIdx.x) * 4;
    if (idx < n) {
        float4 v = *reinterpret_cast<const float4*>(in + idx);
        u32 p0 = (u32)f2bf(v.x) | ((u32)f2bf(v.y) << 16);
        u32 p1 = (u32)f2bf(v.z) | ((u32)f2bf(v.w) << 16);
        u32* o = (u32*)(out + idx);
        o[0] = p0; o[1] = p1;
    }
}

// ---------------- transpose + cast (f32 RxC -> bf16 CxR) ----------------
__global__ __launch_bounds__(256) void transpose_cast_f32_bf16(
    const float* __restrict__ in, u16* __restrict__ out, int R, int Cc)
{
    __shared__ float tile[32][33];
    int c0 = blockIdx.x * 32, r0 = blockIdx.y * 32;
    int tx = threadIdx.x & 31, ty = threadIdx.x >> 5;  // 32 x 8
#pragma unroll
    for (int i = 0; i < 4; ++i)
        tile[ty + i * 8][tx] = in[(size_t)(r0 + ty + i * 8) * Cc + c0 + tx];
    __syncthreads();
#pragma unroll
    for (int i = 0; i < 4; ++i)
        out[(size_t)(c0 + ty + i * 8) * R + r0 + tx] = f2bf(tile[tx][ty + i * 8]);
}

// ---------------- batched bf16 transpose (z, R, Cc) -> (z, Cc, R) ----------------
__global__ __launch_bounds__(256) void transpose_bf16_batched(
    const u16* __restrict__ in, u16* __restrict__ out, int R, int Cc)
{
    __shared__ u16 tile[32][33];
    int c0 = blockIdx.x * 32, r0 = blockIdx.y * 32;
    size_t zb = (size_t)blockIdx.z * R * Cc;
    int tx = threadIdx.x & 31, ty = threadIdx.x >> 5;
#pragma unroll
    for (int i = 0; i < 4; ++i)
        tile[ty + i * 8][tx] = in[zb + (size_t)(r0 + ty + i * 8) * Cc + c0 + tx];
    __syncthreads();
#pragma unroll
    for (int i = 0; i < 4; ++i)
        out[zb + (size_t)(c0 + ty + i * 8) * R + r0 + tx] = tile[tx][ty + i * 8];
}

// ======== 8-phase MFMA GEMM: C[M,N] = A[M,K]*Bt[N,K]^T + bias ========
// R9 schedule (best measured). R17: bf16 epilogue is LDS-coalesced —
// deposit bias-added tile into dead staging LDS (hi-XOR swizzle, 2-way
// banks) then stream out 512B/row dwordx4 segments. Fixes the 2.17x
// WRITE amplification (32B scalar row-chunks < 64B HBM burst).
#define STA(KT2, KK, BUF)                                                  \
  { _Pragma("unroll") for (int i_ = 0; i_ < LA; ++i_)                      \
      gload16(gA[i_] + ((KT2) << 6) + (KK) * 32,                           \
              (char*)&As[BUF][KK][0] + i_ * 8192 + w * 1024); }
#define STB(KT2, KK, BUF)                                                  \
  { _Pragma("unroll") for (int i_ = 0; i_ < 2; ++i_)                       \
      gload16(gB[i_] + ((KT2) << 6) + (KK) * 32,                           \
              (char*)&Bs[BUF][KK][0] + i_ * 8192 + w * 1024); }
#define RDA(DST, BUF, KK, MHALF)                                           \
  { _Pragma("unroll") for (int m_ = 0; m_ < MH; ++m_)                      \
      DST[m_] = *reinterpret_cast<const bf16x8*>(                          \
          aLane + ((BUF) * 2 + (KK)) * ABLKB + ((MHALF) * MH + m_) * 1024); }
#define RDB(DST, BUF, KK)                                                  \
  { _Pragma("unroll") for (int n_ = 0; n_ < 4; ++n_)                       \
      DST[n_] = *reinterpret_cast<const bf16x8*>(                          \
          bLane + ((BUF) * 2 + (KK)) * 16384 + n_ * 1024); }
#define KBODY(KT, CUR)                                                     \
  {                                                                        \
    const int kt_ = (KT);                                                  \
    bf16x8 af0[MH], af1[MH], af2[MH], af3[MH], bf0[4], bf1[4];             \
    RDA(af0, CUR, 0, 0); RDB(bf0, CUR, 0); RDA(af1, CUR, 0, 1);            \
    if (kt_ + 1 < NT) STB(kt_ + 1, 1, CUR ^ 1);                            \
    __builtin_amdgcn_s_barrier();                                          \
    __builtin_amdgcn_s_setprio(1);                                         \
    _Pragma("unroll") for (int m = 0; m < MH; ++m)                         \
      _Pragma("unroll") for (int n = 0; n < 4; ++n)                        \
        acc[m][n] = __builtin_amdgcn_mfma_f32_16x16x32_bf16(               \
            af0[m], bf0[n], acc[m][n], 0, 0, 0);                           \
    __builtin_amdgcn_s_setprio(0);                                         \
    __builtin_amdgcn_s_barrier();                                          \
    RDA(af2, CUR, 1, 0); RDB(bf1, CUR, 1);                                 \
    if (kt_ + 2 < NT) STA(kt_ + 2, 0, CUR);                                \
    __builtin_amdgcn_s_barrier();                                          \
    __builtin_amdgcn_s_setprio(1);                                         \
    _Pragma("unroll") for (int m = 0; m < MH; ++m)                         \
      _Pragma("unroll") for (int n = 0; n < 4; ++n)                        \
        acc[MH + m][n] = __builtin_amdgcn_mfma_f32_16x16x32_bf16(          \
            af1[m], bf0[n], acc[MH + m][n], 0, 0, 0);                      \
    __builtin_amdgcn_s_setprio(0);                                         \
    __builtin_amdgcn_s_barrier();                                          \
    RDA(af3, CUR, 1, 1);                                                   \
    if (kt_ + 2 < NT) STB(kt_ + 2, 0, CUR);                                \
    __builtin_amdgcn_s_barrier();                                          \
    __builtin_amdgcn_s_setprio(1);                                         \
    _Pragma("unroll") for (int m = 0; m < MH; ++m)                         \
      _Pragma("unroll") for (int n = 0; n < 4; ++n)                        \
        acc[m][n] = __builtin_amdgcn_mfma_f32_16x16x32_bf16(               \
            af2[m], bf1[n], acc[m][n], 0, 0, 0);                           \
    __builtin_amdgcn_s_setprio(0);                                         \
    __builtin_amdgcn_s_barrier();                                          \
    if (kt_ + 2 < NT) STA(kt_ + 2, 1, CUR);                                \
    __builtin_amdgcn_s_barrier();                                          \
    __builtin_amdgcn_s_setprio(1);                                         \
    _Pragma("unroll") for (int m = 0; m < MH; ++m)                         \
      _Pragma("unroll") for (int n = 0; n < 4; ++n)                        \
        acc[MH + m][n] = __builtin_amdgcn_mfma_f32_16x16x32_bf16(          \
            af3[m], bf1[n], acc[MH + m][n], 0, 0, 0);                      \
    __builtin_amdgcn_s_setprio(0);                                         \
    if (kt_ + 1 < NT) {                                                    \
      if (kt_ + 2 < NT) {                                                  \
        if constexpr (MFRAG == 8)                                          \
          asm volatile("s_waitcnt vmcnt(6)" ::: "memory");                 \
        else                                                               \
          asm volatile("s_waitcnt vmcnt(4)" ::: "memory");                 \
      } else {                                                             \
        asm volatile("s_waitcnt vmcnt(0)" ::: "memory");                   \
      }                                                                    \
    }                                                                      \
    __builtin_amdgcn_s_barrier();                                          \
  }

template <int MFRAG, int OUT_BF16>
__global__ __launch_bounds__(512, 2) void gemm8(
    const u16* __restrict__ A, const u16* __restrict__ Bt,
    const float* __restrict__ bias, void* __restrict__ Cv,
    int M, int N, int K)
{
    constexpr int MH = MFRAG / 2;        // m-frags per m-half
    constexpr int LA = MFRAG / 4;        // gload16 per A half-tile per wave
    constexpr int ABLKB = MFRAG * 2048;  // bytes per As[buf][kk] block
    // flat SM: As = SM[0 .. MFRAG*4096), Bs = SM[MFRAG*4096 .. +32768)
    __shared__ __attribute__((aligned(16))) u16 SM[MFRAG * 4096 + 32768];
    u16 (*As)[2][MFRAG * 1024] = reinterpret_cast<u16(*)[2][MFRAG * 1024]>(SM);
    u16 (*Bs)[2][8192]         = reinterpret_cast<u16(*)[2][8192]>(SM + MFRAG * 4096);

    int tid = threadIdx.x, lane = tid & 63, w = tid >> 6;
    int l16 = lane & 15, hi = (lane >> 4) & 3;
    int wm = w >> 2, wn = w & 3;

    // bijective XCD swizzle (nwg % 8 == 0 for all our grids)
    int gx = gridDim.x, nwg = gx * gridDim.y;
    int id = blockIdx.y * gx + blockIdx.x;
    int nid = (id & 7) * (nwg >> 3) + (id >> 3);
    int brow = (nid % gx) * (MFRAG * 32), bcol = (nid / gx) * 256;

    const int NT = K >> 6;
    f32x4 acc[MFRAG][4] = {};

    // hoisted lane-constant addressing
    u32 abase = (u32)l16 * 64 + (u32)hi * 16;
    u32 aoff  = abase ^ (((abase >> 7) & 7) << 4);
    const char* aLane = (const char*)SM + wm * (MFRAG * 1024) + aoff;
    const char* bLane = (const char*)(SM + MFRAG * 4096) + wn * 4096 + aoff;

    const u16* gA[LA];
    const u16* gB[2];
#pragma unroll
    for (int i = 0; i < LA; ++i) {
        u32 off = (u32)i * 8192 + (u32)w * 1024 + ((u32)lane << 4);
        u32 g = off ^ (((off >> 7) & 7) << 4);
        gA[i] = A + (size_t)(brow + (g >> 6)) * K + ((g >> 4) & 3) * 8;
    }
#pragma unroll
    for (int i = 0; i < 2; ++i) {
        u32 off = (u32)i * 8192 + (u32)w * 1024 + ((u32)lane << 4);
        u32 g = off ^ (((off >> 7) & 7) << 4);
        gB[i] = Bt + (size_t)(bcol + (g >> 6)) * K + ((g >> 4) & 3) * 8;
    }

    // prologue: tile0 all 4 halves + tile1 {A0, B0, A1}; drain tile0
    STA(0, 0, 0); STB(0, 0, 0); STA(0, 1, 0); STB(0, 1, 0);
    if (NT > 1) {
        STA(1, 0, 1); STB(1, 0, 1); STA(1, 1, 1);
        if constexpr (MFRAG == 8) asm volatile("s_waitcnt vmcnt(6)" ::: "memory");
        else                      asm volatile("s_waitcnt vmcnt(4)" ::: "memory");
    } else {
        asm volatile("s_waitcnt vmcnt(0)" ::: "memory");
    }
    __builtin_amdgcn_s_barrier();

    for (int kt = 0; kt < NT; kt += 2) {   // NT even (K=2048)
        KBODY(kt, 0);
        KBODY(kt + 1, 1);
    }

    // ---- epilogue ----
    if constexpr (OUT_BF16) {
        // LDS-coalesced bf16 writeout: two passes of PR rows x 256 cols.
        constexpr int PR = MFRAG * 16;          // rows per pass
#pragma unroll
        for (int p = 0; p < 2; ++p) {
            __syncthreads();                    // staging LDS dead / pass done
            if (wm == p) {
#pragma unroll
                for (int n = 0; n < 4; ++n) {
                    int cl = wn * 64 + n * 16 + l16;
                    float bv = bias[bcol + cl];
                    int cls = cl ^ (hi << 4);   // bank-spread swizzle
#pragma unroll
                    for (int m = 0; m < MFRAG; ++m) {
#pragma unroll
                        for (int j = 0; j < 4; ++j) {
                            int rl = m * 16 + hi * 4 + j;
                            SM[rl * 256 + cls] = f2bf(acc[m][n][j] + bv);
                        }
                    }
                }
            }
            __syncthreads();
            // stream out: 512B contiguous per row, 16B per thread-chunk
            for (int i = tid; i < PR * 32; i += 512) {
                int off = i * 16;               // byte offset in tile
                int rl = off >> 9;
                int cb = off & 511;
                int src = (off & ~511) | (cb ^ ((((u32)rl >> 2) & 3) << 5));
                *reinterpret_cast<f32x4*>(
                    (char*)Cv + ((size_t)(brow + p * PR + rl) * N + bcol) * 2 + cb) =
                    *reinterpret_cast<const f32x4*>((const char*)SM + src);
            }
        }
    } else {
#pragma unroll
        for (int n = 0; n < 4; ++n) {
            int col = bcol + wn * 64 + n * 16 + l16;
            float bv = bias[col];
#pragma unroll
            for (int m = 0; m < MFRAG; ++m) {
#pragma unroll
                for (int j = 0; j < 4; ++j) {
                    int row = brow + wm * (MFRAG * 16) + m * 16 + hi * 4 + j;
                    ((float*)Cv)[(size_t)row * N + col] = acc[m][n][j] + bv;
                }
            }
        }
    }
}
#undef STA
#undef STB
#undef RDA
#undef RDB
#undef KBODY

// ---------------- RoPE + scatter q/k/v (u32/float2 vectorized) ----------------
__global__ __launch_bounds__(256) void rope_scatter(
    const u16* __restrict__ qkv,
    const float* __restrict__ fcos, const float* __restrict__ fsin,
    u16* __restrict__ qb, u16* __restrict__ kb, u16* __restrict__ vb,
    float* __restrict__ kc, float* __restrict__ vc)
{
    int bt = blockIdx.x;
    int b = bt >> 11, t = bt & 2047;
    const u16* row = qkv + (size_t)bt * NQKV;
#pragma unroll
    for (int s = threadIdx.x; s < NQKV / 2; s += 256) {
        int col = s * 2;
        u32 pair = *reinterpret_cast<const u32*>(row + col);
        float xr = bf2f((u16)pair), xi = bf2f((u16)(pair >> 16));
        if (col < C_) {                       // q
            int h = col >> 7, d = col & 127;
            int fi = t * 64 + (d >> 1);
            float c = fcos[fi], sn = fsin[fi];
            size_t o = ((size_t)(b * NH_ + h) * T_ + t) * HS_ + d;
            *reinterpret_cast<u32*>(qb + o) =
                pack2bf(xr * c - xi * sn, xr * sn + xi * c);
        } else if (col < C_ + NKVH_ * HS_) {  // k
            int cc = col - C_;
            int h = cc >> 7, d = cc & 127;
            int fi = t * 64 + (d >> 1);
            float c = fcos[fi], sn = fsin[fi];
            float yr = xr * c - xi * sn, yi = xr * sn + xi * c;
            size_t o = ((size_t)(b * NKVH_ + h) * T_ + t) * HS_ + d;
            *reinterpret_cast<u32*>(kb + o) = pack2bf(yr, yi);
            *reinterpret_cast<float2*>(kc + o) = make_float2(yr, yi);
        } else {                               // v
            int cc = col - (C_ + NKVH_ * HS_);
            int h = cc >> 7, d = cc & 127;
            size_t o = ((size_t)(b * NKVH_ + h) * T_ + t) * HS_ + d;
            *reinterpret_cast<u32*>(vb + o) = pair;
            *reinterpret_cast<float2*>(vc + o) = make_float2(xr, xi);
        }
    }
}

// ---------------- flash attention (causal, GQA), 32x32 swapped-QK ----------------
// R4-verified form (84-85 us): QBLK=128 (4 waves x 32 q-rows), KVBLK=64,
// K/V dbuf + XOR-swizzle, sum-15 co-resident pairing, NO setprio (-5% measured).
#define STAGE_KV(it_, buf_)                                               \
  {                                                                       \
    int _it = (it_);                                                      \
    _Pragma("unroll")                                                     \
    for (int i = 0; i < 4; ++i) {                                         \
      int chunk = w * 4 + i;                                              \
      int rk = chunk * 4 + (lane >> 4);                                   \
      int ck = ((lane & 15) ^ (rk & 7)) << 3;                             \
      gload16(Kp + (size_t)(_it * 64 + rk) * HS_ + ck,                    \
              (char*)Ks[buf_] + chunk * 1024);                            \
      int rv = chunk * 8 + (lane >> 3);                                   \
      int cv = ((lane & 7) ^ (rv & 7)) << 3;                              \
      gload16(Vp + (size_t)rv * T_ + _it * 64 + cv,                       \
              (char*)Vs[buf_] + chunk * 1024);                            \
    }                                                                     \
  }

__global__ __launch_bounds__(256, 2) void attn_kernel(
    const u16* __restrict__ qb,   // (B, NH, T, HS)
    const u16* __restrict__ kb,   // (B, NKVH, T, HS)
    const u16* __restrict__ vt,   // (B, NKVH, HS, T)
    u16* __restrict__ aout)       // (B, T, C) bf16
{
    __shared__ __attribute__((aligned(16))) u16 Ks[2][64 * 128];
    __shared__ __attribute__((aligned(16))) u16 Vs[2][128 * 64];

    // load-balance remap: co-resident pair (n, n+256) gets qt summing to 15
    int xx = blockIdx.x, yy = blockIdx.y;
    int qt = (yy < 16) ? (15 - xx) : xx;
    int bh = yy, b = bh >> 4, h = bh & 15, kvh = h >> 2;
    int lane = threadIdx.x & 63, w = threadIdx.x >> 6;
    int l32 = lane & 31, l5 = lane >> 5;
    int xorm = (l32 & 7) << 3;               // element-space XOR for LDS reads
    int koff = 8 * l5;

    const u16* Qp = qb + ((size_t)(b * NH_ + h) * T_ + qt * 128 + w * 32) * HS_;
    const u16* Kp = kb + (size_t)(b * NKVH_ + kvh) * T_ * HS_;
    const u16* Vp = vt + (size_t)(b * NKVH_ + kvh) * HS_ * T_;

    // Q as B-operand frags: row = l32 (q), k = kd*16 + 8*l5 + [0..7]
    bf16x8 qf[8];
#pragma unroll
    for (int kd = 0; kd < 8; ++kd)
        qf[kd] = *reinterpret_cast<const bf16x8*>(
            Qp + (size_t)l32 * HS_ + kd * 16 + koff);

    f32x16 o[4] = {};
    float m = -1e30f, lrow = 0.f;
    int qg = qt * 128 + w * 32 + l32;        // this lane's q row
    int qmaxw = qt * 128 + w * 32 + 31;

    int ntiles = 2 * qt + 2;
    STAGE_KV(0, 0);

    for (int it = 0; it < ntiles; ++it) {
        int buf = it & 1;
        __syncthreads();                     // tile `it` resident
        if (it + 1 < ntiles) STAGE_KV(it + 1, buf ^ 1);

        if (it * 64 <= qmaxw) {              // wave has unmasked work here
            const u16* Kbase = Ks[buf];
            const u16* Vbase = Vs[buf];

            // ---- S = K Q^T : D[kv][q], q = l32 lane-local ----
            f32x16 sacc[2] = {};
#pragma unroll
            for (int kt2 = 0; kt2 < 2; ++kt2)
#pragma unroll
                for (int kd = 0; kd < 8; ++kd) {
                    bf16x8 kf = *reinterpret_cast<const bf16x8*>(
                        Kbase + (kt2 * 32 + l32) * 128 + ((kd * 16 + koff) ^ xorm));
                    sacc[kt2] = __builtin_amdgcn_mfma_f32_32x32x16_bf16(
                        kf, qf[kd], sacc[kt2], 0, 0, 0);
                }

            // ---- causal mask (raw scores; exp folds the scale) ----
            if (it * 64 + 63 > qt * 128 + w * 32) {
#pragma unroll
                for (int kt2 = 0; kt2 < 2; ++kt2)
#pragma unroll
                    for (int r = 0; r < 16; ++r) {
                        int kvg = it * 64 + kt2 * 32 + (r & 3) + 8 * (r >> 2) + 4 * l5;
                        if (kvg > qg) sacc[kt2][r] = -1e30f;
                    }
            }

            // ---- row max (tree + 1 cross-half shuffle) ----
            float mx;
            {
                float t8[8];
#pragma unroll
                for (int i = 0; i < 8; ++i) {
                    float a = fmaxf(sacc[0][i], sacc[0][i + 8]);
                    float c = fmaxf(sacc[1][i], sacc[1][i + 8]);
                    t8[i] = fmaxf(a, c);
                }
                float t4a = fmaxf(t8[0], t8[1]), t4b = fmaxf(t8[2], t8[3]);
                float t4c = fmaxf(t8[4], t8[5]), t4d = fmaxf(t8[6], t8[7]);
                mx = fmaxf(fmaxf(t4a, t4b), fmaxf(t4c, t4d));
                mx = fmaxf(mx, __shfl_xor(mx, 32));
            }

            // ---- defer-max: rescale only when max grew past threshold ----
            if (!__all(mx <= m + THR_RAW)) {
                float nm = fmaxf(m, mx);
                float al = exp2f(CC * (m - nm));
                m = nm;
                lrow *= al;
#pragma unroll
                for (int r = 0; r < 16; ++r) {
                    float af = __shfl(al, (r & 3) + 8 * (r >> 2) + 4 * l5, 64);
                    o[0][r] *= af; o[1][r] *= af; o[2][r] *= af; o[3][r] *= af;
                }
            }
            float mcm = -CC * m;

            // ---- P = 2^(CC*s - CC*m), row sum ----
            f32x16 p[2];
#pragma unroll
            for (int kt2 = 0; kt2 < 2; ++kt2)
#pragma unroll
                for (int r = 0; r < 16; ++r)
                    p[kt2][r] = exp2f(__builtin_fmaf(CC, sacc[kt2][r], mcm));
            {
                float s8[8];
#pragma unroll
                for (int i = 0; i < 8; ++i)
                    s8[i] = (p[0][i] + p[0][i + 8]) + (p[1][i] + p[1][i + 8]);
                float s4a = s8[0] + s8[1], s4b = s8[2] + s8[3];
                float s4c = s8[4] + s8[5], s4d = s8[6] + s8[7];
                float rs = (s4a + s4b) + (s4c + s4d);
                rs += __shfl_xor(rs, 32);
                lrow += rs;
            }

            // ---- PV: build A-frags in-register (cvt_pk + permlane32_swap) ----
#pragma unroll
            for (int ks = 0; ks < 4; ++ks) {
                int e = ks & 1, kh = ks >> 1;
                u32 a0 = cvtpk(p[kh][8 * e + 0], p[kh][8 * e + 1]);
                u32 a1 = cvtpk(p[kh][8 * e + 2], p[kh][8 * e + 3]);
                u32 b0 = cvtpk(p[kh][8 * e + 4], p[kh][8 * e + 5]);
                u32 b1 = cvtpk(p[kh][8 * e + 6], p[kh][8 * e + 7]);
                u32x2 s0 = __builtin_amdgcn_permlane32_swap(a0, b0, false, false);
                u32x2 s1 = __builtin_amdgcn_permlane32_swap(a1, b1, false, false);
                union { u32 u[4]; bf16x8 v; } pu;
                pu.u[0] = s0[0]; pu.u[1] = s1[0]; pu.u[2] = s0[1]; pu.u[3] = s1[1];
                bf16x8 pf = pu.v;
#pragma unroll
                for (int dt = 0; dt < 4; ++dt) {
                    bf16x8 vf = *reinterpret_cast<const bf16x8*>(
                        Vbase + (dt * 32 + l32) * 64 + ((ks * 16 + koff) ^ xorm));
                    o[dt] = __builtin_amdgcn_mfma_f32_32x32x16_bf16(
                        pf, vf, o[dt], 0, 0, 0);
                }
            }
        }
    }

    // ---- epilogue: normalize (broadcast 1/l to reg-dim) and store ----
    float inv = 1.0f / lrow;
#pragma unroll
    for (int r = 0; r < 16; ++r) {
        int ql = (r & 3) + 8 * (r >> 2) + 4 * l5;
        float iv = __shfl(inv, ql, 64);
        int trow = qt * 128 + w * 32 + ql;
        size_t base = ((size_t)b * T_ + trow) * C_ + h * HS_ + l32;
#pragma unroll
        for (int dt = 0; dt < 4; ++dt)
            aout[base + dt * 32] = f2bf(o[dt][r] * iv);
    }
}

// ---------------- launch ----------------
extern "C" void kernel_launch(void* const* d_in, const int* in_sizes, int n_in,
                              void* d_out, int out_size, void* d_ws, size_t ws_size,
                              hipStream_t stream)
{
    const float* x      = (const float*)d_in[0];
    const float* w_qkv  = (const float*)d_in[1];
    const float* b_qkv  = (const float*)d_in[2];
    const float* w_proj = (const float*)d_in[3];
    const float* b_proj = (const float*)d_in[4];
    const float* fcos   = (const float*)d_in[5];
    const float* fsin   = (const float*)d_in[6];

    float* y  = (float*)d_out;
    float* kc = y + (size_t)B_ * T_ * C_;
    float* vc = kc + (size_t)B_ * NKVH_ * T_ * HS_;

    // R5-proven workspace layout (71.3 MB)
    char* ws = (char*)d_ws;
    u16* xb     = (u16*)(ws);
    u16* wprojT = (u16*)(ws);
    u16* wqkvT = (u16*)(ws + 16777216);
    u16* kbuf  = (u16*)(ws + 16777216);
    u16* vbuf  = (u16*)(ws + 16777216 + 4194304);
    u16* vtb   = (u16*)(ws + 16777216 + 8388608);
    u16* qkv  = (u16*)(ws + 29360128);
    u16* aout = (u16*)(ws + 29360128);
    u16* qbuf = (u16*)(ws + 54525952);

    cast_f32_bf16<<<M_ * C_ / 1024, 256, 0, stream>>>(x, xb, M_ * C_);
    transpose_cast_f32_bf16<<<dim3(NQKV / 32, C_ / 32), 256, 0, stream>>>(
        w_qkv, wqkvT, C_, NQKV);
    gemm8<8, 1><<<dim3(M_ / 256, NQKV / 256), 512, 0, stream>>>(
        xb, wqkvT, b_qkv, qkv, M_, NQKV, C_);
    rope_scatter<<<M_, 256, 0, stream>>>(qkv, fcos, fsin, qbuf, kbuf, vbuf, kc, vc);
    transpose_bf16_batched<<<dim3(HS_ / 32, T_ / 32, B_ * NKVH_), 256, 0, stream>>>(
        vbuf, vtb, T_, HS_);
    transpose_cast_f32_bf16<<<dim3(C_ / 32, C_ / 32), 256, 0, stream>>>(
        w_proj, wprojT, C_, C_);
    attn_kernel<<<dim3(T_ / 128, B_ * NH_), 256, 0, stream>>>(qbuf, kbuf, vtb, aout);
    gemm8<4, 0><<<dim3(M_ / 128, C_ / 256), 512, 0, stream>>>(
        aout, wprojT, b_proj, y, M_, C_, C_);
}

// Round 18
// 210.923 us; speedup vs baseline: 1.3644x; 1.0198x over previous
//
#include <hip/hip_runtime.h>

typedef unsigned short u16;
typedef unsigned int u32;

#define B_    2
#define T_    2048
#define C_    2048
#define NH_   16
#define NKVH_ 4
#define HS_   128
#define NQKV  3072
#define M_    4096   // B*T
#define SCALE 0.08838834764831845f
#define CC    0.12751742f     // SCALE * log2(e)
#define THR_RAW 62.0f         // defer-max threshold (raw-score units, ~8/CC)

typedef __bf16 bf16x8 __attribute__((ext_vector_type(8)));
typedef float  f32x4  __attribute__((ext_vector_type(4)));
typedef float  f32x16 __attribute__((ext_vector_type(16)));
typedef unsigned int u32x2 __attribute__((ext_vector_type(2)));

__device__ __forceinline__ float bf2f(u16 u) {
    union { u32 i; float f; } x; x.i = ((u32)u) << 16; return x.f;
}
__device__ __forceinline__ u16 f2bf(float f) {
    union { float f; u32 i; } x; x.f = f;
    u32 r = x.i + 0x7fffu + ((x.i >> 16) & 1u);
    return (u16)(r >> 16);
}
__device__ __forceinline__ u32 pack2bf(float lo, float hi) {
    return (u32)f2bf(lo) | ((u32)f2bf(hi) << 16);
}
__device__ __forceinline__ u32 cvtpk(float lo, float hi) {
    u32 r; asm("v_cvt_pk_bf16_f32 %0, %1, %2" : "=v"(r) : "v"(lo), "v"(hi));
    return r;
}

// async global->LDS, 16B per lane; LDS dest = wave-uniform base + lane*16
__device__ __forceinline__ void gload16(const void* g, void* l) {
    __builtin_amdgcn_global_load_lds(
        (const __attribute__((address_space(1))) u32*)g,
        (__attribute__((address_space(3))) u32*)l,
        16, 0, 0);
}

// ---------------- fused prep: cast x + transpose w_qkv + transpose w_proj ----
// Block ranges: [0,8192) cast x; [8192,14336) w_qkv T; [14336,18432) w_proj T.
// All three are independent memory-bound passes; fusing removes 2 dispatch
// boundaries and backfills kernel tails.
__global__ __launch_bounds__(256) void prep_kernel(
    const float* __restrict__ x,      u16* __restrict__ xb,
    const float* __restrict__ w_qkv,  u16* __restrict__ wqkvT,
    const float* __restrict__ w_proj, u16* __restrict__ wprojT)
{
    __shared__ float tile[32][33];
    int bid = blockIdx.x;
    if (bid < 8192) {
        int idx = (bid * 256 + threadIdx.x) * 4;
        float4 v = *reinterpret_cast<const float4*>(x + idx);
        u32 p0 = (u32)f2bf(v.x) | ((u32)f2bf(v.y) << 16);
        u32 p1 = (u32)f2bf(v.z) | ((u32)f2bf(v.w) << 16);
        u32* o = (u32*)(xb + idx);
        o[0] = p0; o[1] = p1;
    } else if (bid < 14336) {
        int tb = bid - 8192;
        int c0 = (tb % 96) * 32, r0 = (tb / 96) * 32;   // in (C_, NQKV)
        int tx = threadIdx.x & 31, ty = threadIdx.x >> 5;
#pragma unroll
        for (int i = 0; i < 4; ++i)
            tile[ty + i * 8][tx] = w_qkv[(size_t)(r0 + ty + i * 8) * NQKV + c0 + tx];
        __syncthreads();
#pragma unroll
        for (int i = 0; i < 4; ++i)
            wqkvT[(size_t)(c0 + ty + i * 8) * C_ + r0 + tx] = f2bf(tile[tx][ty + i * 8]);
    } else {
        int tb = bid - 14336;
        int c0 = (tb % 64) * 32, r0 = (tb / 64) * 32;   // in (C_, C_)
        int tx = threadIdx.x & 31, ty = threadIdx.x >> 5;
#pragma unroll
        for (int i = 0; i < 4; ++i)
            tile[ty + i * 8][tx] = w_proj[(size_t)(r0 + ty + i * 8) * C_ + c0 + tx];
        __syncthreads();
#pragma unroll
        for (int i = 0; i < 4; ++i)
            wprojT[(size_t)(c0 + ty + i * 8) * C_ + r0 + tx] = f2bf(tile[tx][ty + i * 8]);
    }
}

// ---------------- batched bf16 transpose (z, R, Cc) -> (z, Cc, R) ----------------
__global__ __launch_bounds__(256) void transpose_bf16_batched(
    const u16* __restrict__ in, u16* __restrict__ out, int R, int Cc)
{
    __shared__ u16 tile[32][33];
    int c0 = blockIdx.x * 32, r0 = blockIdx.y * 32;
    size_t zb = (size_t)blockIdx.z * R * Cc;
    int tx = threadIdx.x & 31, ty = threadIdx.x >> 5;
#pragma unroll
    for (int i = 0; i < 4; ++i)
        tile[ty + i * 8][tx] = in[zb + (size_t)(r0 + ty + i * 8) * Cc + c0 + tx];
    __syncthreads();
#pragma unroll
    for (int i = 0; i < 4; ++i)
        out[zb + (size_t)(c0 + ty + i * 8) * R + r0 + tx] = tile[tx][ty + i * 8];
}

// ======== 8-phase MFMA GEMM: C[M,N] = A[M,K]*Bt[N,K]^T + bias ========
// R9 schedule + R17 LDS-coalesced bf16 epilogue (WRITE 54.7->24.6 MB).
#define STA(KT2, KK, BUF)                                                  \
  { _Pragma("unroll") for (int i_ = 0; i_ < LA; ++i_)                      \
      gload16(gA[i_] + ((KT2) << 6) + (KK) * 32,                           \
              (char*)&As[BUF][KK][0] + i_ * 8192 + w * 1024); }
#define STB(KT2, KK, BUF)                                                  \
  { _Pragma("unroll") for (int i_ = 0; i_ < 2; ++i_)                       \
      gload16(gB[i_] + ((KT2) << 6) + (KK) * 32,                           \
              (char*)&Bs[BUF][KK][0] + i_ * 8192 + w * 1024); }
#define RDA(DST, BUF, KK, MHALF)                                           \
  { _Pragma("unroll") for (int m_ = 0; m_ < MH; ++m_)                      \
      DST[m_] = *reinterpret_cast<const bf16x8*>(                          \
          aLane + ((BUF) * 2 + (KK)) * ABLKB + ((MHALF) * MH + m_) * 1024); }
#define RDB(DST, BUF, KK)                                                  \
  { _Pragma("unroll") for (int n_ = 0; n_ < 4; ++n_)                       \
      DST[n_] = *reinterpret_cast<const bf16x8*>(                          \
          bLane + ((BUF) * 2 + (KK)) * 16384 + n_ * 1024); }
#define KBODY(KT, CUR)                                                     \
  {                                                                        \
    const int kt_ = (KT);                                                  \
    bf16x8 af0[MH], af1[MH], af2[MH], af3[MH], bf0[4], bf1[4];             \
    RDA(af0, CUR, 0, 0); RDB(bf0, CUR, 0); RDA(af1, CUR, 0, 1);            \
    if (kt_ + 1 < NT) STB(kt_ + 1, 1, CUR ^ 1);                            \
    __builtin_amdgcn_s_barrier();                                          \
    __builtin_amdgcn_s_setprio(1);                                         \
    _Pragma("unroll") for (int m = 0; m < MH; ++m)                         \
      _Pragma("unroll") for (int n = 0; n < 4; ++n)                        \
        acc[m][n] = __builtin_amdgcn_mfma_f32_16x16x32_bf16(               \
            af0[m], bf0[n], acc[m][n], 0, 0, 0);                           \
    __builtin_amdgcn_s_setprio(0);                                         \
    __builtin_amdgcn_s_barrier();                                          \
    RDA(af2, CUR, 1, 0); RDB(bf1, CUR, 1);                                 \
    if (kt_ + 2 < NT) STA(kt_ + 2, 0, CUR);                                \
    __builtin_amdgcn_s_barrier();                                          \
    __builtin_amdgcn_s_setprio(1);                                         \
    _Pragma("unroll") for (int m = 0; m < MH; ++m)                         \
      _Pragma("unroll") for (int n = 0; n < 4; ++n)                        \
        acc[MH + m][n] = __builtin_amdgcn_mfma_f32_16x16x32_bf16(          \
            af1[m], bf0[n], acc[MH + m][n], 0, 0, 0);                      \
    __builtin_amdgcn_s_setprio(0);                                         \
    __builtin_amdgcn_s_barrier();                                          \
    RDA(af3, CUR, 1, 1);                                                   \
    if (kt_ + 2 < NT) STB(kt_ + 2, 0, CUR);                                \
    __builtin_amdgcn_s_barrier();                                          \
    __builtin_amdgcn_s_setprio(1);                                         \
    _Pragma("unroll") for (int m = 0; m < MH; ++m)                         \
      _Pragma("unroll") for (int n = 0; n < 4; ++n)                        \
        acc[m][n] = __builtin_amdgcn_mfma_f32_16x16x32_bf16(               \
            af2[m], bf1[n], acc[m][n], 0, 0, 0);                           \
    __builtin_amdgcn_s_setprio(0);                                         \
    __builtin_amdgcn_s_barrier();                                          \
    if (kt_ + 2 < NT) STA(kt_ + 2, 1, CUR);                                \
    __builtin_amdgcn_s_barrier();                                          \
    __builtin_amdgcn_s_setprio(1);                                         \
    _Pragma("unroll") for (int m = 0; m < MH; ++m)                         \
      _Pragma("unroll") for (int n = 0; n < 4; ++n)                        \
        acc[MH + m][n] = __builtin_amdgcn_mfma_f32_16x16x32_bf16(          \
            af3[m], bf1[n], acc[MH + m][n], 0, 0, 0);                      \
    __builtin_amdgcn_s_setprio(0);                                         \
    if (kt_ + 1 < NT) {                                                    \
      if (kt_ + 2 < NT) {                                                  \
        if constexpr (MFRAG == 8)                                          \
          asm volatile("s_waitcnt vmcnt(6)" ::: "memory");                 \
        else                                                               \
          asm volatile("s_waitcnt vmcnt(4)" ::: "memory");                 \
      } else {                                                             \
        asm volatile("s_waitcnt vmcnt(0)" ::: "memory");                   \
      }                                                                    \
    }                                                                      \
    __builtin_amdgcn_s_barrier();                                          \
  }

template <int MFRAG, int OUT_BF16>
__global__ __launch_bounds__(512, 2) void gemm8(
    const u16* __restrict__ A, const u16* __restrict__ Bt,
    const float* __restrict__ bias, void* __restrict__ Cv,
    int M, int N, int K)
{
    constexpr int MH = MFRAG / 2;        // m-frags per m-half
    constexpr int LA = MFRAG / 4;        // gload16 per A half-tile per wave
    constexpr int ABLKB = MFRAG * 2048;  // bytes per As[buf][kk] block
    __shared__ __attribute__((aligned(16))) u16 SM[MFRAG * 4096 + 32768];
    u16 (*As)[2][MFRAG * 1024] = reinterpret_cast<u16(*)[2][MFRAG * 1024]>(SM);
    u16 (*Bs)[2][8192]         = reinterpret_cast<u16(*)[2][8192]>(SM + MFRAG * 4096);

    int tid = threadIdx.x, lane = tid & 63, w = tid >> 6;
    int l16 = lane & 15, hi = (lane >> 4) & 3;
    int wm = w >> 2, wn = w & 3;

    // bijective XCD swizzle (nwg % 8 == 0 for all our grids)
    int gx = gridDim.x, nwg = gx * gridDim.y;
    int id = blockIdx.y * gx + blockIdx.x;
    int nid = (id & 7) * (nwg >> 3) + (id >> 3);
    int brow = (nid % gx) * (MFRAG * 32), bcol = (nid / gx) * 256;

    const int NT = K >> 6;
    f32x4 acc[MFRAG][4] = {};

    // hoisted lane-constant addressing
    u32 abase = (u32)l16 * 64 + (u32)hi * 16;
    u32 aoff  = abase ^ (((abase >> 7) & 7) << 4);
    const char* aLane = (const char*)SM + wm * (MFRAG * 1024) + aoff;
    const char* bLane = (const char*)(SM + MFRAG * 4096) + wn * 4096 + aoff;

    const u16* gA[LA];
    const u16* gB[2];
#pragma unroll
    for (int i = 0; i < LA; ++i) {
        u32 off = (u32)i * 8192 + (u32)w * 1024 + ((u32)lane << 4);
        u32 g = off ^ (((off >> 7) & 7) << 4);
        gA[i] = A + (size_t)(brow + (g >> 6)) * K + ((g >> 4) & 3) * 8;
    }
#pragma unroll
    for (int i = 0; i < 2; ++i) {
        u32 off = (u32)i * 8192 + (u32)w * 1024 + ((u32)lane << 4);
        u32 g = off ^ (((off >> 7) & 7) << 4);
        gB[i] = Bt + (size_t)(bcol + (g >> 6)) * K + ((g >> 4) & 3) * 8;
    }

    // prologue: tile0 all 4 halves + tile1 {A0, B0, A1}; drain tile0
    STA(0, 0, 0); STB(0, 0, 0); STA(0, 1, 0); STB(0, 1, 0);
    if (NT > 1) {
        STA(1, 0, 1); STB(1, 0, 1); STA(1, 1, 1);
        if constexpr (MFRAG == 8) asm volatile("s_waitcnt vmcnt(6)" ::: "memory");
        else                      asm volatile("s_waitcnt vmcnt(4)" ::: "memory");
    } else {
        asm volatile("s_waitcnt vmcnt(0)" ::: "memory");
    }
    __builtin_amdgcn_s_barrier();

    for (int kt = 0; kt < NT; kt += 2) {   // NT even (K=2048)
        KBODY(kt, 0);
        KBODY(kt + 1, 1);
    }

    // ---- epilogue ----
    if constexpr (OUT_BF16) {
        constexpr int PR = MFRAG * 16;          // rows per pass
#pragma unroll
        for (int p = 0; p < 2; ++p) {
            __syncthreads();
            if (wm == p) {
#pragma unroll
                for (int n = 0; n < 4; ++n) {
                    int cl = wn * 64 + n * 16 + l16;
                    float bv = bias[bcol + cl];
                    int cls = cl ^ (hi << 4);
#pragma unroll
                    for (int m = 0; m < MFRAG; ++m) {
#pragma unroll
                        for (int j = 0; j < 4; ++j) {
                            int rl = m * 16 + hi * 4 + j;
                            SM[rl * 256 + cls] = f2bf(acc[m][n][j] + bv);
                        }
                    }
                }
            }
            __syncthreads();
            for (int i = tid; i < PR * 32; i += 512) {
                int off = i * 16;
                int rl = off >> 9;
                int cb = off & 511;
                int src = (off & ~511) | (cb ^ ((((u32)rl >> 2) & 3) << 5));
                *reinterpret_cast<f32x4*>(
                    (char*)Cv + ((size_t)(brow + p * PR + rl) * N + bcol) * 2 + cb) =
                    *reinterpret_cast<const f32x4*>((const char*)SM + src);
            }
        }
    } else {
#pragma unroll
        for (int n = 0; n < 4; ++n) {
            int col = bcol + wn * 64 + n * 16 + l16;
            float bv = bias[col];
#pragma unroll
            for (int m = 0; m < MFRAG; ++m) {
#pragma unroll
                for (int j = 0; j < 4; ++j) {
                    int row = brow + wm * (MFRAG * 16) + m * 16 + hi * 4 + j;
                    ((float*)Cv)[(size_t)row * N + col] = acc[m][n][j] + bv;
                }
            }
        }
    }
}
#undef STA
#undef STB
#undef RDA
#undef RDB
#undef KBODY

// ---------------- RoPE + scatter q/k/v (u32/float2 vectorized) ----------------
__global__ __launch_bounds__(256) void rope_scatter(
    const u16* __restrict__ qkv,
    const float* __restrict__ fcos, const float* __restrict__ fsin,
    u16* __restrict__ qb, u16* __restrict__ kb, u16* __restrict__ vb,
    float* __restrict__ kc, float* __restrict__ vc)
{
    int bt = blockIdx.x;
    int b = bt >> 11, t = bt & 2047;
    const u16* row = qkv + (size_t)bt * NQKV;
#pragma unroll
    for (int s = threadIdx.x; s < NQKV / 2; s += 256) {
        int col = s * 2;
        u32 pair = *reinterpret_cast<const u32*>(row + col);
        float xr = bf2f((u16)pair), xi = bf2f((u16)(pair >> 16));
        if (col < C_) {                       // q
            int h = col >> 7, d = col & 127;
            int fi = t * 64 + (d >> 1);
            float c = fcos[fi], sn = fsin[fi];
            size_t o = ((size_t)(b * NH_ + h) * T_ + t) * HS_ + d;
            *reinterpret_cast<u32*>(qb + o) =
                pack2bf(xr * c - xi * sn, xr * sn + xi * c);
        } else if (col < C_ + NKVH_ * HS_) {  // k
            int cc = col - C_;
            int h = cc >> 7, d = cc & 127;
            int fi = t * 64 + (d >> 1);
            float c = fcos[fi], sn = fsin[fi];
            float yr = xr * c - xi * sn, yi = xr * sn + xi * c;
            size_t o = ((size_t)(b * NKVH_ + h) * T_ + t) * HS_ + d;
            *reinterpret_cast<u32*>(kb + o) = pack2bf(yr, yi);
            *reinterpret_cast<float2*>(kc + o) = make_float2(yr, yi);
        } else {                               // v
            int cc = col - (C_ + NKVH_ * HS_);
            int h = cc >> 7, d = cc & 127;
            size_t o = ((size_t)(b * NKVH_ + h) * T_ + t) * HS_ + d;
            *reinterpret_cast<u32*>(vb + o) = pair;
            *reinterpret_cast<float2*>(vc + o) = make_float2(xr, xi);
        }
    }
}

// ---------------- flash attention (causal, GQA), 32x32 swapped-QK ----------------
// R4-verified form (84-85 us): QBLK=128 (4 waves x 32 q-rows), KVBLK=64,
// K/V dbuf + XOR-swizzle, sum-15 co-resident pairing, NO setprio (-5% measured).
#define STAGE_KV(it_, buf_)                                               \
  {                                                                       \
    int _it = (it_);                                                      \
    _Pragma("unroll")                                                     \
    for (int i = 0; i < 4; ++i) {                                         \
      int chunk = w * 4 + i;                                              \
      int rk = chunk * 4 + (lane >> 4);                                   \
      int ck = ((lane & 15) ^ (rk & 7)) << 3;                             \
      gload16(Kp + (size_t)(_it * 64 + rk) * HS_ + ck,                    \
              (char*)Ks[buf_] + chunk * 1024);                            \
      int rv = chunk * 8 + (lane >> 3);                                   \
      int cv = ((lane & 7) ^ (rv & 7)) << 3;                              \
      gload16(Vp + (size_t)rv * T_ + _it * 64 + cv,                       \
              (char*)Vs[buf_] + chunk * 1024);                            \
    }                                                                     \
  }

__global__ __launch_bounds__(256, 2) void attn_kernel(
    const u16* __restrict__ qb,   // (B, NH, T, HS)
    const u16* __restrict__ kb,   // (B, NKVH, T, HS)
    const u16* __restrict__ vt,   // (B, NKVH, HS, T)
    u16* __restrict__ aout)       // (B, T, C) bf16
{
    __shared__ __attribute__((aligned(16))) u16 Ks[2][64 * 128];
    __shared__ __attribute__((aligned(16))) u16 Vs[2][128 * 64];

    // load-balance remap: co-resident pair (n, n+256) gets qt summing to 15
    int xx = blockIdx.x, yy = blockIdx.y;
    int qt = (yy < 16) ? (15 - xx) : xx;
    int bh = yy, b = bh >> 4, h = bh & 15, kvh = h >> 2;
    int lane = threadIdx.x & 63, w = threadIdx.x >> 6;
    int l32 = lane & 31, l5 = lane >> 5;
    int xorm = (l32 & 7) << 3;               // element-space XOR for LDS reads
    int koff = 8 * l5;

    const u16* Qp = qb + ((size_t)(b * NH_ + h) * T_ + qt * 128 + w * 32) * HS_;
    const u16* Kp = kb + (size_t)(b * NKVH_ + kvh) * T_ * HS_;
    const u16* Vp = vt + (size_t)(b * NKVH_ + kvh) * HS_ * T_;

    // Q as B-operand frags: row = l32 (q), k = kd*16 + 8*l5 + [0..7]
    bf16x8 qf[8];
#pragma unroll
    for (int kd = 0; kd < 8; ++kd)
        qf[kd] = *reinterpret_cast<const bf16x8*>(
            Qp + (size_t)l32 * HS_ + kd * 16 + koff);

    f32x16 o[4] = {};
    float m = -1e30f, lrow = 0.f;
    int qg = qt * 128 + w * 32 + l32;        // this lane's q row
    int qmaxw = qt * 128 + w * 32 + 31;

    int ntiles = 2 * qt + 2;
    STAGE_KV(0, 0);

    for (int it = 0; it < ntiles; ++it) {
        int buf = it & 1;
        __syncthreads();                     // tile `it` resident
        if (it + 1 < ntiles) STAGE_KV(it + 1, buf ^ 1);

        if (it * 64 <= qmaxw) {              // wave has unmasked work here
            const u16* Kbase = Ks[buf];
            const u16* Vbase = Vs[buf];

            // ---- S = K Q^T : D[kv][q], q = l32 lane-local ----
            f32x16 sacc[2] = {};
#pragma unroll
            for (int kt2 = 0; kt2 < 2; ++kt2)
#pragma unroll
                for (int kd = 0; kd < 8; ++kd) {
                    bf16x8 kf = *reinterpret_cast<const bf16x8*>(
                        Kbase + (kt2 * 32 + l32) * 128 + ((kd * 16 + koff) ^ xorm));
                    sacc[kt2] = __builtin_amdgcn_mfma_f32_32x32x16_bf16(
                        kf, qf[kd], sacc[kt2], 0, 0, 0);
                }

            // ---- causal mask (raw scores; exp folds the scale) ----
            if (it * 64 + 63 > qt * 128 + w * 32) {
#pragma unroll
                for (int kt2 = 0; kt2 < 2; ++kt2)
#pragma unroll
                    for (int r = 0; r < 16; ++r) {
                        int kvg = it * 64 + kt2 * 32 + (r & 3) + 8 * (r >> 2) + 4 * l5;
                        if (kvg > qg) sacc[kt2][r] = -1e30f;
                    }
            }

            // ---- row max (tree + 1 cross-half shuffle) ----
            float mx;
            {
                float t8[8];
#pragma unroll
                for (int i = 0; i < 8; ++i) {
                    float a = fmaxf(sacc[0][i], sacc[0][i + 8]);
                    float c = fmaxf(sacc[1][i], sacc[1][i + 8]);
                    t8[i] = fmaxf(a, c);
                }
                float t4a = fmaxf(t8[0], t8[1]), t4b = fmaxf(t8[2], t8[3]);
                float t4c = fmaxf(t8[4], t8[5]), t4d = fmaxf(t8[6], t8[7]);
                mx = fmaxf(fmaxf(t4a, t4b), fmaxf(t4c, t4d));
                mx = fmaxf(mx, __shfl_xor(mx, 32));
            }

            // ---- defer-max: rescale only when max grew past threshold ----
            if (!__all(mx <= m + THR_RAW)) {
                float nm = fmaxf(m, mx);
                float al = exp2f(CC * (m - nm));
                m = nm;
                lrow *= al;
#pragma unroll
                for (int r = 0; r < 16; ++r) {
                    float af = __shfl(al, (r & 3) + 8 * (r >> 2) + 4 * l5, 64);
                    o[0][r] *= af; o[1][r] *= af; o[2][r] *= af; o[3][r] *= af;
                }
            }
            float mcm = -CC * m;

            // ---- P = 2^(CC*s - CC*m), row sum ----
            f32x16 p[2];
#pragma unroll
            for (int kt2 = 0; kt2 < 2; ++kt2)
#pragma unroll
                for (int r = 0; r < 16; ++r)
                    p[kt2][r] = exp2f(__builtin_fmaf(CC, sacc[kt2][r], mcm));
            {
                float s8[8];
#pragma unroll
                for (int i = 0; i < 8; ++i)
                    s8[i] = (p[0][i] + p[0][i + 8]) + (p[1][i] + p[1][i + 8]);
                float s4a = s8[0] + s8[1], s4b = s8[2] + s8[3];
                float s4c = s8[4] + s8[5], s4d = s8[6] + s8[7];
                float rs = (s4a + s4b) + (s4c + s4d);
                rs += __shfl_xor(rs, 32);
                lrow += rs;
            }

            // ---- PV: build A-frags in-register (cvt_pk + permlane32_swap) ----
#pragma unroll
            for (int ks = 0; ks < 4; ++ks) {
                int e = ks & 1, kh = ks >> 1;
                u32 a0 = cvtpk(p[kh][8 * e + 0], p[kh][8 * e + 1]);
                u32 a1 = cvtpk(p[kh][8 * e + 2], p[kh][8 * e + 3]);
                u32 b0 = cvtpk(p[kh][8 * e + 4], p[kh][8 * e + 5]);
                u32 b1 = cvtpk(p[kh][8 * e + 6], p[kh][8 * e + 7]);
                u32x2 s0 = __builtin_amdgcn_permlane32_swap(a0, b0, false, false);
                u32x2 s1 = __builtin_amdgcn_permlane32_swap(a1, b1, false, false);
                union { u32 u[4]; bf16x8 v; } pu;
                pu.u[0] = s0[0]; pu.u[1] = s1[0]; pu.u[2] = s0[1]; pu.u[3] = s1[1];
                bf16x8 pf = pu.v;
#pragma unroll
                for (int dt = 0; dt < 4; ++dt) {
                    bf16x8 vf = *reinterpret_cast<const bf16x8*>(
                        Vbase + (dt * 32 + l32) * 64 + ((ks * 16 + koff) ^ xorm));
                    o[dt] = __builtin_amdgcn_mfma_f32_32x32x16_bf16(
                        pf, vf, o[dt], 0, 0, 0);
                }
            }
        }
    }

    // ---- epilogue: normalize (broadcast 1/l to reg-dim) and store ----
    float inv = 1.0f / lrow;
#pragma unroll
    for (int r = 0; r < 16; ++r) {
        int ql = (r & 3) + 8 * (r >> 2) + 4 * l5;
        float iv = __shfl(inv, ql, 64);
        int trow = qt * 128 + w * 32 + ql;
        size_t base = ((size_t)b * T_ + trow) * C_ + h * HS_ + l32;
#pragma unroll
        for (int dt = 0; dt < 4; ++dt)
            aout[base + dt * 32] = f2bf(o[dt][r] * iv);
    }
}

// ---------------- launch ----------------
extern "C" void kernel_launch(void* const* d_in, const int* in_sizes, int n_in,
                              void* d_out, int out_size, void* d_ws, size_t ws_size,
                              hipStream_t stream)
{
    const float* x      = (const float*)d_in[0];
    const float* w_qkv  = (const float*)d_in[1];
    const float* b_qkv  = (const float*)d_in[2];
    const float* w_proj = (const float*)d_in[3];
    const float* b_proj = (const float*)d_in[4];
    const float* fcos   = (const float*)d_in[5];
    const float* fsin   = (const float*)d_in[6];

    float* y  = (float*)d_out;
    float* kc = y + (size_t)B_ * T_ * C_;
    float* vc = kc + (size_t)B_ * NKVH_ * T_ * HS_;

    // workspace layout (79.7 MB): wprojT moved to its own region since it is
    // now written up-front by the fused prep kernel (xb stays live past it).
    char* ws = (char*)d_ws;
    u16* xb     = (u16*)(ws);
    u16* wqkvT  = (u16*)(ws + 16777216);
    u16* kbuf   = (u16*)(ws + 16777216);
    u16* vbuf   = (u16*)(ws + 16777216 + 4194304);
    u16* vtb    = (u16*)(ws + 16777216 + 8388608);
    u16* qkv    = (u16*)(ws + 29360128);
    u16* aout   = (u16*)(ws + 29360128);
    u16* qbuf   = (u16*)(ws + 54525952);
    u16* wprojT = (u16*)(ws + 71303168);   // +8.4MB, total 79.7MB

    // 1. fused prep: cast x + transpose both weight matrices
    prep_kernel<<<18432, 256, 0, stream>>>(x, xb, w_qkv, wqkvT, w_proj, wprojT);
    // 2. qkv = x @ w_qkv + b_qkv  (bf16, LDS-coalesced writeout)
    gemm8<8, 1><<<dim3(M_ / 256, NQKV / 256), 512, 0, stream>>>(
        xb, wqkvT, b_qkv, qkv, M_, NQKV, C_);
    // 3. RoPE + scatter (also writes fp32 k/v caches)
    rope_scatter<<<M_, 256, 0, stream>>>(qkv, fcos, fsin, qbuf, kbuf, vbuf, kc, vc);
    // 4. V -> V^T
    transpose_bf16_batched<<<dim3(HS_ / 32, T_ / 32, B_ * NKVH_), 256, 0, stream>>>(
        vbuf, vtb, T_, HS_);
    // 5. attention
    attn_kernel<<<dim3(T_ / 128, B_ * NH_), 256, 0, stream>>>(qbuf, kbuf, vtb, aout);
    // 6. y = aout @ w_proj + b_proj (fp32)
    gemm8<4, 0><<<dim3(M_ / 128, C_ / 256), 512, 0, stream>>>(
        aout, wprojT, b_proj, y, M_, C_, C_);
}

// Round 19
// 207.818 us; speedup vs baseline: 1.3847x; 1.0149x over previous
//
#include <hip/hip_runtime.h>

typedef unsigned short u16;
typedef unsigned int u32;

#define B_    2
#define T_    2048
#define C_    2048
#define NH_   16
#define NKVH_ 4
#define HS_   128
#define NQKV  3072
#define M_    4096   // B*T
#define SCALE 0.08838834764831845f
#define CC    0.12751742f     // SCALE * log2(e)
#define THR_RAW 62.0f         // defer-max threshold (raw-score units, ~8/CC)

typedef __bf16 bf16x8 __attribute__((ext_vector_type(8)));
typedef float  f32x4  __attribute__((ext_vector_type(4)));
typedef float  f32x16 __attribute__((ext_vector_type(16)));
typedef unsigned int u32x2 __attribute__((ext_vector_type(2)));

__device__ __forceinline__ float bf2f(u16 u) {
    union { u32 i; float f; } x; x.i = ((u32)u) << 16; return x.f;
}
__device__ __forceinline__ u16 f2bf(float f) {
    union { float f; u32 i; } x; x.f = f;
    u32 r = x.i + 0x7fffu + ((x.i >> 16) & 1u);
    return (u16)(r >> 16);
}
__device__ __forceinline__ u32 pack2bf(float lo, float hi) {
    return (u32)f2bf(lo) | ((u32)f2bf(hi) << 16);
}
__device__ __forceinline__ u32 cvtpk(float lo, float hi) {
    u32 r; asm("v_cvt_pk_bf16_f32 %0, %1, %2" : "=v"(r) : "v"(lo), "v"(hi));
    return r;
}

// async global->LDS, 16B per lane; LDS dest = wave-uniform base + lane*16
__device__ __forceinline__ void gload16(const void* g, void* l) {
    __builtin_amdgcn_global_load_lds(
        (const __attribute__((address_space(1))) u32*)g,
        (__attribute__((address_space(3))) u32*)l,
        16, 0, 0);
}

// ---------------- fused prep: cast x + transpose w_qkv + transpose w_proj ----
__global__ __launch_bounds__(256) void prep_kernel(
    const float* __restrict__ x,      u16* __restrict__ xb,
    const float* __restrict__ w_qkv,  u16* __restrict__ wqkvT,
    const float* __restrict__ w_proj, u16* __restrict__ wprojT)
{
    __shared__ float tile[32][33];
    int bid = blockIdx.x;
    if (bid < 8192) {
        int idx = (bid * 256 + threadIdx.x) * 4;
        float4 v = *reinterpret_cast<const float4*>(x + idx);
        u32 p0 = (u32)f2bf(v.x) | ((u32)f2bf(v.y) << 16);
        u32 p1 = (u32)f2bf(v.z) | ((u32)f2bf(v.w) << 16);
        u32* o = (u32*)(xb + idx);
        o[0] = p0; o[1] = p1;
    } else if (bid < 14336) {
        int tb = bid - 8192;
        int c0 = (tb % 96) * 32, r0 = (tb / 96) * 32;   // in (C_, NQKV)
        int tx = threadIdx.x & 31, ty = threadIdx.x >> 5;
#pragma unroll
        for (int i = 0; i < 4; ++i)
            tile[ty + i * 8][tx] = w_qkv[(size_t)(r0 + ty + i * 8) * NQKV + c0 + tx];
        __syncthreads();
#pragma unroll
        for (int i = 0; i < 4; ++i)
            wqkvT[(size_t)(c0 + ty + i * 8) * C_ + r0 + tx] = f2bf(tile[tx][ty + i * 8]);
    } else {
        int tb = bid - 14336;
        int c0 = (tb % 64) * 32, r0 = (tb / 64) * 32;   // in (C_, C_)
        int tx = threadIdx.x & 31, ty = threadIdx.x >> 5;
#pragma unroll
        for (int i = 0; i < 4; ++i)
            tile[ty + i * 8][tx] = w_proj[(size_t)(r0 + ty + i * 8) * C_ + c0 + tx];
        __syncthreads();
#pragma unroll
        for (int i = 0; i < 4; ++i)
            wprojT[(size_t)(c0 + ty + i * 8) * C_ + r0 + tx] = f2bf(tile[tx][ty + i * 8]);
    }
}

// ======== 8-phase MFMA GEMM: C[M,N] = A[M,K]*Bt[N,K]^T + bias ========
// R9 schedule + R17 LDS-coalesced bf16 epilogue (WRITE 54.7->24.6 MB).
#define STA(KT2, KK, BUF)                                                  \
  { _Pragma("unroll") for (int i_ = 0; i_ < LA; ++i_)                      \
      gload16(gA[i_] + ((KT2) << 6) + (KK) * 32,                           \
              (char*)&As[BUF][KK][0] + i_ * 8192 + w * 1024); }
#define STB(KT2, KK, BUF)                                                  \
  { _Pragma("unroll") for (int i_ = 0; i_ < 2; ++i_)                       \
      gload16(gB[i_] + ((KT2) << 6) + (KK) * 32,                           \
              (char*)&Bs[BUF][KK][0] + i_ * 8192 + w * 1024); }
#define RDA(DST, BUF, KK, MHALF)                                           \
  { _Pragma("unroll") for (int m_ = 0; m_ < MH; ++m_)                      \
      DST[m_] = *reinterpret_cast<const bf16x8*>(                          \
          aLane + ((BUF) * 2 + (KK)) * ABLKB + ((MHALF) * MH + m_) * 1024); }
#define RDB(DST, BUF, KK)                                                  \
  { _Pragma("unroll") for (int n_ = 0; n_ < 4; ++n_)                       \
      DST[n_] = *reinterpret_cast<const bf16x8*>(                          \
          bLane + ((BUF) * 2 + (KK)) * 16384 + n_ * 1024); }
#define KBODY(KT, CUR)                                                     \
  {                                                                        \
    const int kt_ = (KT);                                                  \
    bf16x8 af0[MH], af1[MH], af2[MH], af3[MH], bf0[4], bf1[4];             \
    RDA(af0, CUR, 0, 0); RDB(bf0, CUR, 0); RDA(af1, CUR, 0, 1);            \
    if (kt_ + 1 < NT) STB(kt_ + 1, 1, CUR ^ 1);                            \
    __builtin_amdgcn_s_barrier();                                          \
    __builtin_amdgcn_s_setprio(1);                                         \
    _Pragma("unroll") for (int m = 0; m < MH; ++m)                         \
      _Pragma("unroll") for (int n = 0; n < 4; ++n)                        \
        acc[m][n] = __builtin_amdgcn_mfma_f32_16x16x32_bf16(               \
            af0[m], bf0[n], acc[m][n], 0, 0, 0);                           \
    __builtin_amdgcn_s_setprio(0);                                         \
    __builtin_amdgcn_s_barrier();                                          \
    RDA(af2, CUR, 1, 0); RDB(bf1, CUR, 1);                                 \
    if (kt_ + 2 < NT) STA(kt_ + 2, 0, CUR);                                \
    __builtin_amdgcn_s_barrier();                                          \
    __builtin_amdgcn_s_setprio(1);                                         \
    _Pragma("unroll") for (int m = 0; m < MH; ++m)                         \
      _Pragma("unroll") for (int n = 0; n < 4; ++n)                        \
        acc[MH + m][n] = __builtin_amdgcn_mfma_f32_16x16x32_bf16(          \
            af1[m], bf0[n], acc[MH + m][n], 0, 0, 0);                      \
    __builtin_amdgcn_s_setprio(0);                                         \
    __builtin_amdgcn_s_barrier();                                          \
    RDA(af3, CUR, 1, 1);                                                   \
    if (kt_ + 2 < NT) STB(kt_ + 2, 0, CUR);                                \
    __builtin_amdgcn_s_barrier();                                          \
    __builtin_amdgcn_s_setprio(1);                                         \
    _Pragma("unroll") for (int m = 0; m < MH; ++m)                         \
      _Pragma("unroll") for (int n = 0; n < 4; ++n)                        \
        acc[m][n] = __builtin_amdgcn_mfma_f32_16x16x32_bf16(               \
            af2[m], bf1[n], acc[m][n], 0, 0, 0);                           \
    __builtin_amdgcn_s_setprio(0);                                         \
    __builtin_amdgcn_s_barrier();                                          \
    if (kt_ + 2 < NT) STA(kt_ + 2, 1, CUR);                                \
    __builtin_amdgcn_s_barrier();                                          \
    __builtin_amdgcn_s_setprio(1);                                         \
    _Pragma("unroll") for (int m = 0; m < MH; ++m)                         \
      _Pragma("unroll") for (int n = 0; n < 4; ++n)                        \
        acc[MH + m][n] = __builtin_amdgcn_mfma_f32_16x16x32_bf16(          \
            af3[m], bf1[n], acc[MH + m][n], 0, 0, 0);                      \
    __builtin_amdgcn_s_setprio(0);                                         \
    if (kt_ + 1 < NT) {                                                    \
      if (kt_ + 2 < NT) {                                                  \
        if constexpr (MFRAG == 8)                                          \
          asm volatile("s_waitcnt vmcnt(6)" ::: "memory");                 \
        else                                                               \
          asm volatile("s_waitcnt vmcnt(4)" ::: "memory");                 \
      } else {                                                             \
        asm volatile("s_waitcnt vmcnt(0)" ::: "memory");                   \
      }                                                                    \
    }                                                                      \
    __builtin_amdgcn_s_barrier();                                          \
  }

template <int MFRAG, int OUT_BF16>
__global__ __launch_bounds__(512, 2) void gemm8(
    const u16* __restrict__ A, const u16* __restrict__ Bt,
    const float* __restrict__ bias, void* __restrict__ Cv,
    int M, int N, int K)
{
    constexpr int MH = MFRAG / 2;        // m-frags per m-half
    constexpr int LA = MFRAG / 4;        // gload16 per A half-tile per wave
    constexpr int ABLKB = MFRAG * 2048;  // bytes per As[buf][kk] block
    __shared__ __attribute__((aligned(16))) u16 SM[MFRAG * 4096 + 32768];
    u16 (*As)[2][MFRAG * 1024] = reinterpret_cast<u16(*)[2][MFRAG * 1024]>(SM);
    u16 (*Bs)[2][8192]         = reinterpret_cast<u16(*)[2][8192]>(SM + MFRAG * 4096);

    int tid = threadIdx.x, lane = tid & 63, w = tid >> 6;
    int l16 = lane & 15, hi = (lane >> 4) & 3;
    int wm = w >> 2, wn = w & 3;

    // bijective XCD swizzle (nwg % 8 == 0 for all our grids)
    int gx = gridDim.x, nwg = gx * gridDim.y;
    int id = blockIdx.y * gx + blockIdx.x;
    int nid = (id & 7) * (nwg >> 3) + (id >> 3);
    int brow = (nid % gx) * (MFRAG * 32), bcol = (nid / gx) * 256;

    const int NT = K >> 6;
    f32x4 acc[MFRAG][4] = {};

    // hoisted lane-constant addressing
    u32 abase = (u32)l16 * 64 + (u32)hi * 16;
    u32 aoff  = abase ^ (((abase >> 7) & 7) << 4);
    const char* aLane = (const char*)SM + wm * (MFRAG * 1024) + aoff;
    const char* bLane = (const char*)(SM + MFRAG * 4096) + wn * 4096 + aoff;

    const u16* gA[LA];
    const u16* gB[2];
#pragma unroll
    for (int i = 0; i < LA; ++i) {
        u32 off = (u32)i * 8192 + (u32)w * 1024 + ((u32)lane << 4);
        u32 g = off ^ (((off >> 7) & 7) << 4);
        gA[i] = A + (size_t)(brow + (g >> 6)) * K + ((g >> 4) & 3) * 8;
    }
#pragma unroll
    for (int i = 0; i < 2; ++i) {
        u32 off = (u32)i * 8192 + (u32)w * 1024 + ((u32)lane << 4);
        u32 g = off ^ (((off >> 7) & 7) << 4);
        gB[i] = Bt + (size_t)(bcol + (g >> 6)) * K + ((g >> 4) & 3) * 8;
    }

    // prologue: tile0 all 4 halves + tile1 {A0, B0, A1}; drain tile0
    STA(0, 0, 0); STB(0, 0, 0); STA(0, 1, 0); STB(0, 1, 0);
    if (NT > 1) {
        STA(1, 0, 1); STB(1, 0, 1); STA(1, 1, 1);
        if constexpr (MFRAG == 8) asm volatile("s_waitcnt vmcnt(6)" ::: "memory");
        else                      asm volatile("s_waitcnt vmcnt(4)" ::: "memory");
    } else {
        asm volatile("s_waitcnt vmcnt(0)" ::: "memory");
    }
    __builtin_amdgcn_s_barrier();

    for (int kt = 0; kt < NT; kt += 2) {   // NT even (K=2048)
        KBODY(kt, 0);
        KBODY(kt + 1, 1);
    }

    // ---- epilogue ----
    if constexpr (OUT_BF16) {
        constexpr int PR = MFRAG * 16;          // rows per pass
#pragma unroll
        for (int p = 0; p < 2; ++p) {
            __syncthreads();
            if (wm == p) {
#pragma unroll
                for (int n = 0; n < 4; ++n) {
                    int cl = wn * 64 + n * 16 + l16;
                    float bv = bias[bcol + cl];
                    int cls = cl ^ (hi << 4);
#pragma unroll
                    for (int m = 0; m < MFRAG; ++m) {
#pragma unroll
                        for (int j = 0; j < 4; ++j) {
                            int rl = m * 16 + hi * 4 + j;
                            SM[rl * 256 + cls] = f2bf(acc[m][n][j] + bv);
                        }
                    }
                }
            }
            __syncthreads();
            for (int i = tid; i < PR * 32; i += 512) {
                int off = i * 16;
                int rl = off >> 9;
                int cb = off & 511;
                int src = (off & ~511) | (cb ^ ((((u32)rl >> 2) & 3) << 5));
                *reinterpret_cast<f32x4*>(
                    (char*)Cv + ((size_t)(brow + p * PR + rl) * N + bcol) * 2 + cb) =
                    *reinterpret_cast<const f32x4*>((const char*)SM + src);
            }
        }
    } else {
#pragma unroll
        for (int n = 0; n < 4; ++n) {
            int col = bcol + wn * 64 + n * 16 + l16;
            float bv = bias[col];
#pragma unroll
            for (int m = 0; m < MFRAG; ++m) {
#pragma unroll
                for (int j = 0; j < 4; ++j) {
                    int row = brow + wm * (MFRAG * 16) + m * 16 + hi * 4 + j;
                    ((float*)Cv)[(size_t)row * N + col] = acc[m][n][j] + bv;
                }
            }
        }
    }
}
#undef STA
#undef STB
#undef RDA
#undef RDB
#undef KBODY

// ------- fused RoPE + scatter q/k + V f32 cache + V transpose (qkv -> vtb) ----
// Blocks [0, M_): per-(b,t) RoPE for q/k (+ f32 kc), V branch writes only the
// f32 vc cache. Blocks [M_, M_+2048): 32x32 LDS-tile transpose reading V
// directly from qkv (V needs no RoPE) -> vtb (b,kvh,HS,T). Removes the vbuf
// relay (8.4 MB traffic) and one dispatch boundary.
__global__ __launch_bounds__(256) void rope_vt_kernel(
    const u16* __restrict__ qkv,
    const float* __restrict__ fcos, const float* __restrict__ fsin,
    u16* __restrict__ qb, u16* __restrict__ kb, u16* __restrict__ vtb,
    float* __restrict__ kc, float* __restrict__ vc)
{
    __shared__ u16 tile[32][33];
    int bid = blockIdx.x;
    if (bid < M_) {
        int b = bid >> 11, t = bid & 2047;
        const u16* row = qkv + (size_t)bid * NQKV;
#pragma unroll
        for (int s = threadIdx.x; s < NQKV / 2; s += 256) {
            int col = s * 2;
            u32 pair = *reinterpret_cast<const u32*>(row + col);
            float xr = bf2f((u16)pair), xi = bf2f((u16)(pair >> 16));
            if (col < C_) {                       // q
                int h = col >> 7, d = col & 127;
                int fi = t * 64 + (d >> 1);
                float c = fcos[fi], sn = fsin[fi];
                size_t o = ((size_t)(b * NH_ + h) * T_ + t) * HS_ + d;
                *reinterpret_cast<u32*>(qb + o) =
                    pack2bf(xr * c - xi * sn, xr * sn + xi * c);
            } else if (col < C_ + NKVH_ * HS_) {  // k
                int cc = col - C_;
                int h = cc >> 7, d = cc & 127;
                int fi = t * 64 + (d >> 1);
                float c = fcos[fi], sn = fsin[fi];
                float yr = xr * c - xi * sn, yi = xr * sn + xi * c;
                size_t o = ((size_t)(b * NKVH_ + h) * T_ + t) * HS_ + d;
                *reinterpret_cast<u32*>(kb + o) = pack2bf(yr, yi);
                *reinterpret_cast<float2*>(kc + o) = make_float2(yr, yi);
            } else {                               // v: f32 cache only
                int cc = col - (C_ + NKVH_ * HS_);
                int h = cc >> 7, d = cc & 127;
                size_t o = ((size_t)(b * NKVH_ + h) * T_ + t) * HS_ + d;
                *reinterpret_cast<float2*>(vc + o) = make_float2(xr, xi);
            }
        }
    } else {
        // V transpose tile: tb = hs-tile (4) x t-tile (64) x z (8)
        int tb = bid - M_;
        int hs0 = (tb & 3) * 32;
        int t0  = ((tb >> 2) & 63) * 32;
        int z   = tb >> 8;                 // b*NKVH + kvh
        int b = z >> 2, kvh = z & 3;
        int tx = threadIdx.x & 31, ty = threadIdx.x >> 5;
        int csrc = 2560 + kvh * 128 + hs0;
#pragma unroll
        for (int i = 0; i < 4; ++i)
            tile[ty + i * 8][tx] = qkv[(size_t)(b * T_ + t0 + ty + i * 8) * NQKV + csrc + tx];
        __syncthreads();
        size_t zb = (size_t)z * HS_ * T_;
#pragma unroll
        for (int i = 0; i < 4; ++i)
            vtb[zb + (size_t)(hs0 + ty + i * 8) * T_ + t0 + tx] = tile[tx][ty + i * 8];
    }
}

// ---------------- flash attention (causal, GQA), 32x32 swapped-QK ----------------
// R4-verified form (84-85 us): QBLK=128 (4 waves x 32 q-rows), KVBLK=64,
// K/V dbuf + XOR-swizzle, sum-15 co-resident pairing, NO setprio (-5% measured).
#define STAGE_KV(it_, buf_)                                               \
  {                                                                       \
    int _it = (it_);                                                      \
    _Pragma("unroll")                                                     \
    for (int i = 0; i < 4; ++i) {                                         \
      int chunk = w * 4 + i;                                              \
      int rk = chunk * 4 + (lane >> 4);                                   \
      int ck = ((lane & 15) ^ (rk & 7)) << 3;                             \
      gload16(Kp + (size_t)(_it * 64 + rk) * HS_ + ck,                    \
              (char*)Ks[buf_] + chunk * 1024);                            \
      int rv = chunk * 8 + (lane >> 3);                                   \
      int cv = ((lane & 7) ^ (rv & 7)) << 3;                              \
      gload16(Vp + (size_t)rv * T_ + _it * 64 + cv,                       \
              (char*)Vs[buf_] + chunk * 1024);                            \
    }                                                                     \
  }

__global__ __launch_bounds__(256, 2) void attn_kernel(
    const u16* __restrict__ qb,   // (B, NH, T, HS)
    const u16* __restrict__ kb,   // (B, NKVH, T, HS)
    const u16* __restrict__ vt,   // (B, NKVH, HS, T)
    u16* __restrict__ aout)       // (B, T, C) bf16
{
    __shared__ __attribute__((aligned(16))) u16 Ks[2][64 * 128];
    __shared__ __attribute__((aligned(16))) u16 Vs[2][128 * 64];

    // load-balance remap: co-resident pair (n, n+256) gets qt summing to 15
    int xx = blockIdx.x, yy = blockIdx.y;
    int qt = (yy < 16) ? (15 - xx) : xx;
    int bh = yy, b = bh >> 4, h = bh & 15, kvh = h >> 2;
    int lane = threadIdx.x & 63, w = threadIdx.x >> 6;
    int l32 = lane & 31, l5 = lane >> 5;
    int xorm = (l32 & 7) << 3;               // element-space XOR for LDS reads
    int koff = 8 * l5;

    const u16* Qp = qb + ((size_t)(b * NH_ + h) * T_ + qt * 128 + w * 32) * HS_;
    const u16* Kp = kb + (size_t)(b * NKVH_ + kvh) * T_ * HS_;
    const u16* Vp = vt + (size_t)(b * NKVH_ + kvh) * HS_ * T_;

    // Q as B-operand frags: row = l32 (q), k = kd*16 + 8*l5 + [0..7]
    bf16x8 qf[8];
#pragma unroll
    for (int kd = 0; kd < 8; ++kd)
        qf[kd] = *reinterpret_cast<const bf16x8*>(
            Qp + (size_t)l32 * HS_ + kd * 16 + koff);

    f32x16 o[4] = {};
    float m = -1e30f, lrow = 0.f;
    int qg = qt * 128 + w * 32 + l32;        // this lane's q row
    int qmaxw = qt * 128 + w * 32 + 31;

    int ntiles = 2 * qt + 2;
    STAGE_KV(0, 0);

    for (int it = 0; it < ntiles; ++it) {
        int buf = it & 1;
        __syncthreads();                     // tile `it` resident
        if (it + 1 < ntiles) STAGE_KV(it + 1, buf ^ 1);

        if (it * 64 <= qmaxw) {              // wave has unmasked work here
            const u16* Kbase = Ks[buf];
            const u16* Vbase = Vs[buf];

            // ---- S = K Q^T : D[kv][q], q = l32 lane-local ----
            f32x16 sacc[2] = {};
#pragma unroll
            for (int kt2 = 0; kt2 < 2; ++kt2)
#pragma unroll
                for (int kd = 0; kd < 8; ++kd) {
                    bf16x8 kf = *reinterpret_cast<const bf16x8*>(
                        Kbase + (kt2 * 32 + l32) * 128 + ((kd * 16 + koff) ^ xorm));
                    sacc[kt2] = __builtin_amdgcn_mfma_f32_32x32x16_bf16(
                        kf, qf[kd], sacc[kt2], 0, 0, 0);
                }

            // ---- causal mask (raw scores; exp folds the scale) ----
            if (it * 64 + 63 > qt * 128 + w * 32) {
#pragma unroll
                for (int kt2 = 0; kt2 < 2; ++kt2)
#pragma unroll
                    for (int r = 0; r < 16; ++r) {
                        int kvg = it * 64 + kt2 * 32 + (r & 3) + 8 * (r >> 2) + 4 * l5;
                        if (kvg > qg) sacc[kt2][r] = -1e30f;
                    }
            }

            // ---- row max (tree + 1 cross-half shuffle) ----
            float mx;
            {
                float t8[8];
#pragma unroll
                for (int i = 0; i < 8; ++i) {
                    float a = fmaxf(sacc[0][i], sacc[0][i + 8]);
                    float c = fmaxf(sacc[1][i], sacc[1][i + 8]);
                    t8[i] = fmaxf(a, c);
                }
                float t4a = fmaxf(t8[0], t8[1]), t4b = fmaxf(t8[2], t8[3]);
                float t4c = fmaxf(t8[4], t8[5]), t4d = fmaxf(t8[6], t8[7]);
                mx = fmaxf(fmaxf(t4a, t4b), fmaxf(t4c, t4d));
                mx = fmaxf(mx, __shfl_xor(mx, 32));
            }

            // ---- defer-max: rescale only when max grew past threshold ----
            if (!__all(mx <= m + THR_RAW)) {
                float nm = fmaxf(m, mx);
                float al = exp2f(CC * (m - nm));
                m = nm;
                lrow *= al;
#pragma unroll
                for (int r = 0; r < 16; ++r) {
                    float af = __shfl(al, (r & 3) + 8 * (r >> 2) + 4 * l5, 64);
                    o[0][r] *= af; o[1][r] *= af; o[2][r] *= af; o[3][r] *= af;
                }
            }
            float mcm = -CC * m;

            // ---- P = 2^(CC*s - CC*m), row sum ----
            f32x16 p[2];
#pragma unroll
            for (int kt2 = 0; kt2 < 2; ++kt2)
#pragma unroll
                for (int r = 0; r < 16; ++r)
                    p[kt2][r] = exp2f(__builtin_fmaf(CC, sacc[kt2][r], mcm));
            {
                float s8[8];
#pragma unroll
                for (int i = 0; i < 8; ++i)
                    s8[i] = (p[0][i] + p[0][i + 8]) + (p[1][i] + p[1][i + 8]);
                float s4a = s8[0] + s8[1], s4b = s8[2] + s8[3];
                float s4c = s8[4] + s8[5], s4d = s8[6] + s8[7];
                float rs = (s4a + s4b) + (s4c + s4d);
                rs += __shfl_xor(rs, 32);
                lrow += rs;
            }

            // ---- PV: build A-frags in-register (cvt_pk + permlane32_swap) ----
#pragma unroll
            for (int ks = 0; ks < 4; ++ks) {
                int e = ks & 1, kh = ks >> 1;
                u32 a0 = cvtpk(p[kh][8 * e + 0], p[kh][8 * e + 1]);
                u32 a1 = cvtpk(p[kh][8 * e + 2], p[kh][8 * e + 3]);
                u32 b0 = cvtpk(p[kh][8 * e + 4], p[kh][8 * e + 5]);
                u32 b1 = cvtpk(p[kh][8 * e + 6], p[kh][8 * e + 7]);
                u32x2 s0 = __builtin_amdgcn_permlane32_swap(a0, b0, false, false);
                u32x2 s1 = __builtin_amdgcn_permlane32_swap(a1, b1, false, false);
                union { u32 u[4]; bf16x8 v; } pu;
                pu.u[0] = s0[0]; pu.u[1] = s1[0]; pu.u[2] = s0[1]; pu.u[3] = s1[1];
                bf16x8 pf = pu.v;
#pragma unroll
                for (int dt = 0; dt < 4; ++dt) {
                    bf16x8 vf = *reinterpret_cast<const bf16x8*>(
                        Vbase + (dt * 32 + l32) * 64 + ((ks * 16 + koff) ^ xorm));
                    o[dt] = __builtin_amdgcn_mfma_f32_32x32x16_bf16(
                        pf, vf, o[dt], 0, 0, 0);
                }
            }
        }
    }

    // ---- epilogue: normalize (broadcast 1/l to reg-dim) and store ----
    float inv = 1.0f / lrow;
#pragma unroll
    for (int r = 0; r < 16; ++r) {
        int ql = (r & 3) + 8 * (r >> 2) + 4 * l5;
        float iv = __shfl(inv, ql, 64);
        int trow = qt * 128 + w * 32 + ql;
        size_t base = ((size_t)b * T_ + trow) * C_ + h * HS_ + l32;
#pragma unroll
        for (int dt = 0; dt < 4; ++dt)
            aout[base + dt * 32] = f2bf(o[dt][r] * iv);
    }
}

// ---------------- launch ----------------
extern "C" void kernel_launch(void* const* d_in, const int* in_sizes, int n_in,
                              void* d_out, int out_size, void* d_ws, size_t ws_size,
                              hipStream_t stream)
{
    const float* x      = (const float*)d_in[0];
    const float* w_qkv  = (const float*)d_in[1];
    const float* b_qkv  = (const float*)d_in[2];
    const float* w_proj = (const float*)d_in[3];
    const float* b_proj = (const float*)d_in[4];
    const float* fcos   = (const float*)d_in[5];
    const float* fsin   = (const float*)d_in[6];

    float* y  = (float*)d_out;
    float* kc = y + (size_t)B_ * T_ * C_;
    float* vc = kc + (size_t)B_ * NKVH_ * T_ * HS_;

    // workspace layout (79.7 MB); vbuf region now unused (V reads from qkv)
    char* ws = (char*)d_ws;
    u16* xb     = (u16*)(ws);
    u16* wqkvT  = (u16*)(ws + 16777216);
    u16* kbuf   = (u16*)(ws + 16777216);
    u16* vtb    = (u16*)(ws + 16777216 + 8388608);
    u16* qkv    = (u16*)(ws + 29360128);
    u16* aout   = (u16*)(ws + 29360128);
    u16* qbuf   = (u16*)(ws + 54525952);
    u16* wprojT = (u16*)(ws + 71303168);

    // 1. fused prep: cast x + transpose both weight matrices
    prep_kernel<<<18432, 256, 0, stream>>>(x, xb, w_qkv, wqkvT, w_proj, wprojT);
    // 2. qkv = x @ w_qkv + b_qkv  (bf16, LDS-coalesced writeout)
    gemm8<8, 1><<<dim3(M_ / 256, NQKV / 256), 512, 0, stream>>>(
        xb, wqkvT, b_qkv, qkv, M_, NQKV, C_);
    // 3. fused RoPE/scatter + V transpose (writes fp32 caches + vtb)
    rope_vt_kernel<<<M_ + 2048, 256, 0, stream>>>(
        qkv, fcos, fsin, qbuf, kbuf, vtb, kc, vc);
    // 4. attention
    attn_kernel<<<dim3(T_ / 128, B_ * NH_), 256, 0, stream>>>(qbuf, kbuf, vtb, aout);
    // 5. y = aout @ w_proj + b_proj (fp32)
    gemm8<4, 0><<<dim3(M_ / 128, C_ / 256), 512, 0, stream>>>(
        aout, wprojT, b_proj, y, M_, C_, C_);
}